// Round 5
// baseline (4331.636 us; speedup 1.0000x reference)
//
#include <hip/hip_runtime.h>
#include <hip/hip_cooperative_groups.h>
#include <hip/hip_bf16.h>

namespace cg = cooperative_groups;

// OptFlow: forward-additive LK, B=16, k=4, 256x256, 20 iters.
// R3: single cooperative mega-kernel (1024 blocks x 256 thr, 4/CU) with one
//     grid.sync() per LK iteration; parallel 8x8 GJ inversion; p/gate in
//     registers per block. Fallback to the proven R2 chain if coop launch
//     is rejected.
// R4: register-cached template (Ft/gx/gy per pixel, fully unrolled arrays)
//     -> zero temp loads in the 20x hot loop. Values bit-identical.

#define B_   16
#define K_   4
#define H_   256
#define W_   256
#define HW_  (H_*W_)
#define ROWS_PER_BLOCK 16
#define NBLOCKS 1024          // = 16 batches x 64 bands; exactly 4 blocks/CU
#define NITER 20
#define TOL2 1.0e-6

#define MLO 0.99609375f
#define MHI 254.00390625f

// ---------------- ws layout (bytes) ----------------
// g       : [NITER][B_][8] double @ 0        (20480)   g holds 2*(J^T r)
// invH    : [B_][8][8]    double @ 20480    (8192)
// hmpart  : [NBLOCKS][36] double @ 28672    (294912)
// pstore  : [NITER][B_][8] float @ 323584   (10240)   (fallback only)
// gateflag: [NITER][B_]   int    @ 333824   (1280)    (fallback only)
#define WS_G       0
#define WS_INVH    20480
#define WS_HMPART  28672
#define WS_PSTORE  323584
#define WS_GATE    333824

// ===========================================================================
// cooperative mega-kernel
// ===========================================================================
__global__ __launch_bounds__(256, 4) void coop_kernel(
    const float* __restrict__ img, const float* __restrict__ temp,
    const float* __restrict__ init_param, float* __restrict__ out,
    double* __restrict__ g, double* __restrict__ invH,
    double* __restrict__ hmpart)
{
    cg::grid_group grid = cg::this_grid();
    const int bid = blockIdx.x;
    const int b = bid & 15;           // batch -> XCD b%8 pinned (L2 locality)
    const int band = bid >> 4;        // 0..63
    const int kc = band >> 4;
    const int ybase = (band & 15) << 4;
    const int tid = threadIdx.x;

    const float* tb = temp + (size_t)(b * K_ + kc) * HW_;
    const float* ib = img + (size_t)(b * K_ + kc) * HW_;

    const int x = tid;
    const int xmi = max(x - 1, 0), xpi = min(x + 1, W_ - 1);
    const float X = (float)x - 127.5f;
    const int lane = tid & 63, wave = tid >> 6;

    __shared__ double s_red36[4][36];
    __shared__ double s_redq[36][4];
    __shared__ double s_aug[8][16];
    __shared__ double s_invH[64];
    __shared__ double s_red8[4][8];
    __shared__ int s_pr;
    __shared__ double s_pivinv;

    // register-cached template: Ft, raw (2x) gradients per row (static idx only)
    float Ftr[ROWS_PER_BLOCK], gxr[ROWS_PER_BLOCK], gyr[ROWS_PER_BLOCK];

    // ---------------- phase P: Hm partials + fill template cache -----------
    {
        float acc[36];
#pragma unroll
        for (int i = 0; i < 36; ++i) acc[i] = 0.0f;

        float tm = tb[max(ybase - 1, 0) * W_ + x];
        float t0 = tb[ybase * W_ + x];

#pragma unroll
        for (int r = 0; r < ROWS_PER_BLOCK; ++r) {
            const int y = ybase + r;
            const float Y = (float)y - 127.5f;
            const float tp = tb[min(y + 1, H_ - 1) * W_ + x];
            const float txm = tb[y * W_ + xmi];
            const float txp = tb[y * W_ + xpi];
            const float gx2 = txp - txm;   // raw 2x gradients (exact)
            const float gy2 = tp - tm;
            Ftr[r] = t0; gxr[r] = gx2; gyr[r] = gy2;
            tm = t0; t0 = tp;

            const float gx = 0.5f * gx2;   // exact: same value as 0.5f*(txp-txm)
            const float gy = 0.5f * gy2;
            const float s = fmaf(X, gx, Y * gy);
            float j[8];
            j[0] = X * gx; j[1] = Y * gx; j[2] = gx;
            j[3] = X * gy; j[4] = Y * gy; j[5] = gy;
            j[6] = -X * s; j[7] = -Y * s;
            int idx = 0;
#pragma unroll
            for (int a = 0; a < 8; ++a)
#pragma unroll
                for (int c = a; c < 8; ++c) {
                    acc[idx] = fmaf(j[a], j[c], acc[idx]);
                    ++idx;
                }
        }
#pragma unroll
        for (int i = 0; i < 36; ++i) {
            float v = acc[i];
            for (int off = 32; off > 0; off >>= 1) v += __shfl_down(v, off, 64);
            if (lane == 0) s_red36[wave][i] = (double)v;
        }
        __syncthreads();
        if (tid < 36)
            hmpart[(size_t)bid * 36 + tid] =
                s_red36[0][tid] + s_red36[1][tid] + s_red36[2][tid] + s_red36[3][tid];
    }

    grid.sync();  // #1: hmpart complete

    // ---------------- phase I: invert (blocks 0..15), zero g (16..31) ------
    if (bid < 16) {
        if (tid < 144) {
            const int c = tid >> 2, q = tid & 3;
            double s = 0.0;
            for (int m = 0; m < 16; ++m)
                s += hmpart[(size_t)((q * 16 + m) * 16 + b) * 36 + c];
            s_redq[c][q] = s;
        }
        __syncthreads();
        if (tid < 64) {
            const int j = tid >> 3, k2 = tid & 7;
            s_aug[j][8 + k2] = (j == k2) ? 1.0 : 0.0;
        }
        if (tid < 36) {
            const double sum = s_redq[tid][0] + s_redq[tid][1] + s_redq[tid][2] + s_redq[tid][3];
            int a = 0, base = 0;
            for (; a < 8; ++a) {
                const int next = base + (8 - a);
                if (tid < next) break;
                base = next;
            }
            const int cc = a + (tid - base);
            s_aug[a][cc] = sum;
            s_aug[cc][a] = sum;
        }
        __syncthreads();
        // parallel GJ with partial pivoting: 128 threads own (row, col)
        for (int piv = 0; piv < 8; ++piv) {
            if (tid == 0) {
                int pr = piv;
                double pv = fabs(s_aug[piv][piv]);
                for (int rr = piv + 1; rr < 8; ++rr) {
                    const double a2 = fabs(s_aug[rr][piv]);
                    if (a2 > pv) { pv = a2; pr = rr; }
                }
                s_pr = pr;
            }
            __syncthreads();
            const int pr = s_pr;
            if (pr != piv && tid < 16) {
                const double t1 = s_aug[piv][tid];
                s_aug[piv][tid] = s_aug[pr][tid];
                s_aug[pr][tid] = t1;
            }
            __syncthreads();
            if (tid == 0) s_pivinv = 1.0 / s_aug[piv][piv];
            __syncthreads();
            if (tid < 16) s_aug[piv][tid] *= s_pivinv;
            __syncthreads();
            const int r2 = tid >> 4, cc = tid & 15;
            double f = 0.0;
            if (tid < 128 && r2 != piv) f = s_aug[r2][piv];
            __syncthreads();
            if (tid < 128 && r2 != piv) s_aug[r2][cc] -= f * s_aug[piv][cc];
            __syncthreads();
        }
        if (tid < 64) invH[b * 64 + tid] = s_aug[tid >> 3][8 + (tid & 7)];
    } else if (bid < 32) {
        for (int t2 = tid; t2 < NITER * B_ * 8 / 16; t2 += 256)
            g[(bid - 16) * (NITER * B_ * 8 / 16) + t2] = 0.0;
    }

    grid.sync();  // #2: invH + zeroed g visible

    if (tid < 64) s_invH[tid] = invH[b * 64 + tid];
    // s_invH first read happens after the next grid.sync (block barrier incl.)

    float p[8];
#pragma unroll
    for (int j = 0; j < 8; ++j) p[j] = init_param[b * 8 + j];
    int gate = 1;  // ||dp0|| = sqrt(8) > TOL

    for (int it = 0; it < NITER; ++it) {
        if (gate) {
            const float a00 = 1.0f + p[0], a01 = p[1];
            const float a10 = p[3], a11 = 1.0f + p[4];
            const float a20 = p[6], a21 = p[7];
            const float a02c = p[2] + 127.5f;
            const float a12c = p[5] + 127.5f;
            const bool affine = (a20 == 0.0f) && (a21 == 0.0f);

            float acc0 = 0.f, acc1 = 0.f, acc2 = 0.f, acc3 = 0.f;
            float acc4 = 0.f, acc5 = 0.f, acc6 = 0.f, acc7 = 0.f;

#pragma unroll
            for (int r = 0; r < ROWS_PER_BLOCK; ++r) {
                const int y = ybase + r;
                const float Y = (float)y - 127.5f;
                float Xw, Yw;
                if (affine) {
                    Xw = fmaf(a00, X, fmaf(a01, Y, a02c));
                    Yw = fmaf(a10, X, fmaf(a11, Y, a12c));
                } else {
                    const float numx = fmaf(a00, X, fmaf(a01, Y, a02c - 127.5f));
                    const float numy = fmaf(a10, X, fmaf(a11, Y, a12c - 127.5f));
                    const float den = fmaf(a20, X, fmaf(a21, Y, 1.0f));
                    Xw = numx / den + 127.5f;
                    Yw = numy / den + 127.5f;
                }

                const float x0f = floorf(Xw), y0f = floorf(Yw);
                const float wx = Xw - x0f, wy = Yw - y0f;
                const int x0 = (int)x0f, y0 = (int)y0f;
                const int x1 = x0 + 1, y1 = y0 + 1;
                const int xc0 = min(max(x0, 0), W_ - 1), xc1 = min(max(x1, 0), W_ - 1);
                const int yc0 = min(max(y0, 0), H_ - 1), yc1 = min(max(y1, 0), H_ - 1);
                const bool vx0 = (unsigned)x0 < (unsigned)W_, vx1 = (unsigned)x1 < (unsigned)W_;
                const bool vy0 = (unsigned)y0 < (unsigned)H_, vy1 = (unsigned)y1 < (unsigned)H_;

                const int idx00 = yc0 * W_ + xc0;
                const int dxi = xc1 - xc0;
                const int dyi = (yc1 - yc0) * W_;
                float v00 = ib[idx00];
                float v01 = ib[idx00 + dxi];
                float v10 = ib[idx00 + dyi];
                float v11 = ib[idx00 + dyi + dxi];
                v00 = (vx0 && vy0) ? v00 : 0.0f;
                v01 = (vx1 && vy0) ? v01 : 0.0f;
                v10 = (vx0 && vy1) ? v10 : 0.0f;
                v11 = (vx1 && vy1) ? v11 : 0.0f;

                const float top = fmaf(wx, v01 - v00, v00);
                const float bot = fmaf(wx, v11 - v10, v10);
                const float Q = fmaf(wy, bot - top, top);

                const bool mask = (Xw > MLO) & (Xw < MHI) & (Yw > MLO) & (Yw < MHI);

                const float Ft = Ftr[r];           // cached template (no loads)
                const float gx = gxr[r];           // 2x grads (exact), 0.5 in solve
                const float gy = gyr[r];

                const float rr = Q - (mask ? Ft : 0.0f);
                const float rX = rr * X, rY = rr * Y;
                const float s = fmaf(X, gx, Y * gy);
                acc0 = fmaf(gx, rX, acc0);
                acc1 = fmaf(gx, rY, acc1);
                acc2 = fmaf(gx, rr, acc2);
                acc3 = fmaf(gy, rX, acc3);
                acc4 = fmaf(gy, rY, acc4);
                acc5 = fmaf(gy, rr, acc5);
                acc6 = fmaf(-s, rX, acc6);
                acc7 = fmaf(-s, rY, acc7);
            }

            float d8[8] = {acc0, acc1, acc2, acc3, acc4, acc5, acc6, acc7};
#pragma unroll
            for (int j = 0; j < 8; ++j) {
                float v = d8[j];
                for (int off = 32; off > 0; off >>= 1) v += __shfl_down(v, off, 64);
                if (lane == 0) s_red8[wave][j] = (double)v;
            }
            __syncthreads();
            if (tid < 8) {
                const double v = s_red8[0][tid] + s_red8[1][tid] + s_red8[2][tid] + s_red8[3][tid];
                unsafeAtomicAdd(&g[(size_t)(it * B_ + b) * 8 + tid], v);
            }
            __syncthreads();  // protect s_red8 reuse
        }

        grid.sync();  // g[it] complete everywhere

        if (gate) {   // replay solve (bit-identical across all blocks of batch b)
            const double* gp = g + (size_t)(it * B_ + b) * 8;
            double gv[8];
#pragma unroll
            for (int k2 = 0; k2 < 8; ++k2) gv[k2] = gp[k2];
            double nsq = 0.0;
#pragma unroll
            for (int j = 0; j < 6; ++j) {
                double s = 0.0;
#pragma unroll
                for (int k2 = 0; k2 < 8; ++k2) s += s_invH[j * 8 + k2] * gv[k2];
                const double dpj = 0.5 * s;  // exact compensation for 2x grads
                nsq += dpj * dpj;
                p[j] -= (float)dpj;
            }
            gate = (nsq > TOL2) ? 1 : 0;
        }
        // gate==0: dp=0, p frozen, gate stays 0 — matches reference recurrence
    }

    if (bid < 16) {  // b == bid here
        if (tid < 8) out[b * 8 + tid] = p[tid];
        if (tid < 9) {
            float v = (tid < 8) ? p[tid] : 0.0f;
            if (tid == 0 || tid == 4 || tid == 8) v += 1.0f;
            out[B_ * 8 + b * 9 + tid] = v;
        }
    }
}

// ===========================================================================
// fallback chain (R2 kernels, verbatim — proven passing) — used only if the
// cooperative launch is rejected.
// ===========================================================================
__global__ __launch_bounds__(256, 2) void prep_kernel(const float* __restrict__ temp,
                                                      double* __restrict__ hmpart) {
    const int bid = blockIdx.x;
    const int b = bid & 15;
    const int strip = bid >> 4;
    const int tid = threadIdx.x;
    const int kc = strip >> 4;
    const int ybase = (strip & 15) << 4;
    const float* tb = temp + (size_t)(b * K_ + kc) * HW_;

    const int x = tid;
    const int xm = max(x - 1, 0), xp = min(x + 1, W_ - 1);
    const float X = (float)x - 127.5f;

    float acc[36];
#pragma unroll
    for (int i = 0; i < 36; ++i) acc[i] = 0.0f;

    float tm = tb[max(ybase - 1, 0) * W_ + x];
    float t0 = tb[ybase * W_ + x];

#pragma unroll 4
    for (int r = 0; r < ROWS_PER_BLOCK; ++r) {
        const int y = ybase + r;
        const float Y = (float)y - 127.5f;
        const float tp = tb[min(y + 1, H_ - 1) * W_ + x];
        const float txm = tb[y * W_ + xm];
        const float txp = tb[y * W_ + xp];
        const float gx = 0.5f * (txp - txm);
        const float gy = 0.5f * (tp - tm);
        tm = t0; t0 = tp;

        const float s = fmaf(X, gx, Y * gy);
        float j[8];
        j[0] = X * gx; j[1] = Y * gx; j[2] = gx;
        j[3] = X * gy; j[4] = Y * gy; j[5] = gy;
        j[6] = -X * s; j[7] = -Y * s;
        int idx = 0;
#pragma unroll
        for (int a = 0; a < 8; ++a)
#pragma unroll
            for (int c = a; c < 8; ++c) {
                acc[idx] = fmaf(j[a], j[c], acc[idx]);
                ++idx;
            }
    }

    __shared__ double red[4][36];
    const int lane = tid & 63, wave = tid >> 6;
#pragma unroll
    for (int i = 0; i < 36; ++i) {
        double v = (double)acc[i];
        for (int off = 32; off > 0; off >>= 1) v += __shfl_down(v, off, 64);
        if (lane == 0) red[wave][i] = v;
    }
    __syncthreads();
    if (tid < 36)
        hmpart[(size_t)bid * 36 + tid] =
            red[0][tid] + red[1][tid] + red[2][tid] + red[3][tid];
}

__global__ __launch_bounds__(256) void solveh_kernel(const double* __restrict__ hmpart,
                                                     const float* __restrict__ init_param,
                                                     double* __restrict__ invH,
                                                     double* __restrict__ g,
                                                     float* __restrict__ pstore) {
    __shared__ double aug[B_][8][16];
    const int tid = threadIdx.x;

    for (int t = tid; t < NITER * B_ * 8; t += 256) g[t] = 0.0;
    for (int t = tid; t < B_ * 8; t += 256) pstore[t] = init_param[t];

    for (int t = tid; t < B_ * 64; t += 256) {
        const int b = t >> 6, j = (t >> 3) & 7, k = t & 7;
        aug[b][j][8 + k] = (j == k) ? 1.0 : 0.0;
    }
    for (int t = tid; t < B_ * 36; t += 256) {
        const int b = t / 36, c = t % 36;
        double sum = 0.0;
        for (int s = 0; s < 64; ++s) sum += hmpart[(size_t)(s * 16 + b) * 36 + c];
        int a = 0, base = 0;
        for (; a < 8; ++a) {
            const int next = base + (8 - a);
            if (c < next) break;
            base = next;
        }
        const int cc = a + (c - base);
        aug[b][a][cc] = sum;
        aug[b][cc][a] = sum;
    }
    __syncthreads();

    if (tid < B_) {
        double (*A)[16] = aug[tid];
        for (int piv = 0; piv < 8; ++piv) {
            int pr = piv;
            double pv = fabs(A[piv][piv]);
            for (int rr = piv + 1; rr < 8; ++rr) {
                const double a2 = fabs(A[rr][piv]);
                if (a2 > pv) { pv = a2; pr = rr; }
            }
            if (pr != piv)
                for (int c = 0; c < 16; ++c) {
                    const double tmp = A[piv][c]; A[piv][c] = A[pr][c]; A[pr][c] = tmp;
                }
            const double inv = 1.0 / A[piv][piv];
            for (int c = 0; c < 16; ++c) A[piv][c] *= inv;
            for (int rr = 0; rr < 8; ++rr) {
                if (rr == piv) continue;
                const double f = A[rr][piv];
                for (int c = 0; c < 16; ++c) A[rr][c] -= f * A[piv][c];
            }
        }
        for (int j = 0; j < 8; ++j)
            for (int k = 0; k < 8; ++k)
                invH[tid * 64 + j * 8 + k] = A[j][8 + k];
    }
}

__device__ __forceinline__ void solve_step(const double* __restrict__ invHb,
                                           const double* __restrict__ gprev,
                                           const float* __restrict__ pprev,
                                           int gate_prev, float* p, int* gate_out) {
    double dp[8];
#pragma unroll
    for (int j = 0; j < 8; ++j) dp[j] = 0.0;
    if (gate_prev) {
#pragma unroll
        for (int j = 0; j < 6; ++j) {
            double s = 0.0;
#pragma unroll
            for (int k = 0; k < 8; ++k) s += invHb[j * 8 + k] * gprev[k];
            dp[j] = 0.5 * s;
        }
    }
    double nsq = 0.0;
#pragma unroll
    for (int j = 0; j < 8; ++j) nsq += dp[j] * dp[j];
    *gate_out = (nsq > TOL2) ? 1 : 0;
#pragma unroll
    for (int j = 0; j < 8; ++j) p[j] = pprev[j] - (float)dp[j];
}

__global__ __launch_bounds__(256, 4) void iter_kernel(const float* __restrict__ img,
                                                      const float* __restrict__ temp,
                                                      const float* __restrict__ init_param,
                                                      const double* __restrict__ invH,
                                                      double* __restrict__ g,
                                                      float* __restrict__ pstore,
                                                      int* __restrict__ gateflag,
                                                      int iter) {
    const int bid = blockIdx.x;
    const int b = bid & 15;
    const int strip = bid >> 4;
    const int tid = threadIdx.x;

    float p[8];
    int gate;
    if (iter == 0) {
#pragma unroll
        for (int j = 0; j < 8; ++j) p[j] = init_param[b * 8 + j];
        gate = 1;
    } else {
        solve_step(invH + b * 64, g + (size_t)((iter - 1) * B_ + b) * 8,
                   pstore + (size_t)((iter - 1) * B_ + b) * 8,
                   gateflag[(iter - 1) * B_ + b], p, &gate);
    }
    if (tid < 8) pstore[(size_t)(iter * B_ + b) * 8 + tid] = p[tid];
    if (tid == 0) gateflag[iter * B_ + b] = gate;
    if (!gate) return;

    const int kc = strip >> 4;
    const int ybase = (strip & 15) << 4;
    const float* ib = img + (size_t)(b * K_ + kc) * HW_;
    const float* tb = temp + (size_t)(b * K_ + kc) * HW_;

    const float a00 = 1.0f + p[0], a01 = p[1];
    const float a10 = p[3], a11 = 1.0f + p[4];
    const float a20 = p[6], a21 = p[7];
    const float a02c = p[2] + 127.5f;
    const float a12c = p[5] + 127.5f;
    const bool affine = (a20 == 0.0f) && (a21 == 0.0f);

    const int x = tid;
    const int xm = max(x - 1, 0), xp = min(x + 1, W_ - 1);
    const float X = (float)x - 127.5f;

    float acc0 = 0.f, acc1 = 0.f, acc2 = 0.f, acc3 = 0.f;
    float acc4 = 0.f, acc5 = 0.f, acc6 = 0.f, acc7 = 0.f;

    float tm = tb[max(ybase - 1, 0) * W_ + x];
    float t0 = tb[ybase * W_ + x];

#pragma unroll 4
    for (int r = 0; r < ROWS_PER_BLOCK; ++r) {
        const int y = ybase + r;
        const float Y = (float)y - 127.5f;
        float Xw, Yw;
        if (affine) {
            Xw = fmaf(a00, X, fmaf(a01, Y, a02c));
            Yw = fmaf(a10, X, fmaf(a11, Y, a12c));
        } else {
            const float numx = fmaf(a00, X, fmaf(a01, Y, a02c - 127.5f));
            const float numy = fmaf(a10, X, fmaf(a11, Y, a12c - 127.5f));
            const float den = fmaf(a20, X, fmaf(a21, Y, 1.0f));
            Xw = numx / den + 127.5f;
            Yw = numy / den + 127.5f;
        }

        const float x0f = floorf(Xw), y0f = floorf(Yw);
        const float wx = Xw - x0f, wy = Yw - y0f;
        const int x0 = (int)x0f, y0 = (int)y0f;
        const int x1 = x0 + 1, y1 = y0 + 1;
        const int xc0 = min(max(x0, 0), W_ - 1), xc1 = min(max(x1, 0), W_ - 1);
        const int yc0 = min(max(y0, 0), H_ - 1), yc1 = min(max(y1, 0), H_ - 1);
        const bool vx0 = (unsigned)x0 < (unsigned)W_, vx1 = (unsigned)x1 < (unsigned)W_;
        const bool vy0 = (unsigned)y0 < (unsigned)H_, vy1 = (unsigned)y1 < (unsigned)H_;

        const int idx00 = yc0 * W_ + xc0;
        const int dxi = xc1 - xc0;
        const int dyi = (yc1 - yc0) * W_;
        float v00 = ib[idx00];
        float v01 = ib[idx00 + dxi];
        float v10 = ib[idx00 + dyi];
        float v11 = ib[idx00 + dyi + dxi];
        v00 = (vx0 && vy0) ? v00 : 0.0f;
        v01 = (vx1 && vy0) ? v01 : 0.0f;
        v10 = (vx0 && vy1) ? v10 : 0.0f;
        v11 = (vx1 && vy1) ? v11 : 0.0f;

        const float top = fmaf(wx, v01 - v00, v00);
        const float bot = fmaf(wx, v11 - v10, v10);
        const float Q = fmaf(wy, bot - top, top);

        const bool mask = (Xw > MLO) & (Xw < MHI) & (Yw > MLO) & (Yw < MHI);

        const float tpv = tb[min(y + 1, H_ - 1) * W_ + x];
        const float txm = tb[y * W_ + xm];
        const float txp = tb[y * W_ + xp];
        const float Ft = t0;
        const float gx = txp - txm;
        const float gy = tpv - tm;
        tm = t0; t0 = tpv;

        const float rr = Q - (mask ? Ft : 0.0f);
        const float rX = rr * X, rY = rr * Y;
        const float s = fmaf(X, gx, Y * gy);
        acc0 = fmaf(gx, rX, acc0);
        acc1 = fmaf(gx, rY, acc1);
        acc2 = fmaf(gx, rr, acc2);
        acc3 = fmaf(gy, rX, acc3);
        acc4 = fmaf(gy, rY, acc4);
        acc5 = fmaf(gy, rr, acc5);
        acc6 = fmaf(-s, rX, acc6);
        acc7 = fmaf(-s, rY, acc7);
    }

    __shared__ double red[4][8];
    const int lane = tid & 63, wave = tid >> 6;
    float d[8] = {acc0, acc1, acc2, acc3, acc4, acc5, acc6, acc7};
#pragma unroll
    for (int j = 0; j < 8; ++j) {
        float v = d[j];
        for (int off = 32; off > 0; off >>= 1) v += __shfl_down(v, off, 64);
        if (lane == 0) red[wave][j] = (double)v;
    }
    __syncthreads();
    if (tid < 8) {
        const double v = red[0][tid] + red[1][tid] + red[2][tid] + red[3][tid];
        unsafeAtomicAdd(&g[(size_t)(iter * B_ + b) * 8 + tid], v);
    }
}

__global__ void finish_kernel(const double* __restrict__ invH,
                              const double* __restrict__ g,
                              const float* __restrict__ pstore,
                              const int* __restrict__ gateflag,
                              float* __restrict__ out) {
    const int tid = threadIdx.x;
    if (tid < B_) {
        const int b = tid;
        float pf[8];
        int gate_dummy;
        solve_step(invH + b * 64, g + (size_t)((NITER - 1) * B_ + b) * 8,
                   pstore + (size_t)((NITER - 1) * B_ + b) * 8,
                   gateflag[(NITER - 1) * B_ + b], pf, &gate_dummy);
        for (int j = 0; j < 8; ++j) out[b * 8 + j] = pf[j];
        float* Hout = out + B_ * 8 + b * 9;
        for (int idx = 0; idx < 9; ++idx) {
            float v = (idx < 8) ? pf[idx] : 0.0f;
            if (idx == 0 || idx == 4 || idx == 8) v += 1.0f;
            Hout[idx] = v;
        }
    }
}

extern "C" void kernel_launch(void* const* d_in, const int* in_sizes, int n_in,
                              void* d_out, int out_size, void* d_ws, size_t ws_size,
                              hipStream_t stream) {
    (void)in_sizes; (void)n_in; (void)out_size; (void)ws_size;
    const float* img = (const float*)d_in[0];
    const float* temp = (const float*)d_in[1];
    const float* init_param = (const float*)d_in[2];

    float* out = (float*)d_out;
    char* ws = (char*)d_ws;
    double* g = (double*)(ws + WS_G);
    double* invH = (double*)(ws + WS_INVH);
    double* hmpart = (double*)(ws + WS_HMPART);
    float* pstore = (float*)(ws + WS_PSTORE);
    int* gateflag = (int*)(ws + WS_GATE);

    void* kargs[] = {(void*)&img, (void*)&temp, (void*)&init_param,
                     (void*)&out, (void*)&g, (void*)&invH, (void*)&hmpart};
    hipError_t err = hipLaunchCooperativeKernel((const void*)coop_kernel,
                                                dim3(NBLOCKS), dim3(256),
                                                kargs, 0, stream);
    if (err != hipSuccess) {
        // fallback: proven R2 multi-kernel chain
        hipLaunchKernelGGL(prep_kernel, dim3(NBLOCKS), dim3(256), 0, stream, temp, hmpart);
        hipLaunchKernelGGL(solveh_kernel, dim3(1), dim3(256), 0, stream,
                           hmpart, init_param, invH, g, pstore);
        for (int i = 0; i < NITER; ++i) {
            hipLaunchKernelGGL(iter_kernel, dim3(NBLOCKS), dim3(256), 0, stream,
                               img, temp, init_param, invH, g, pstore, gateflag, i);
        }
        hipLaunchKernelGGL(finish_kernel, dim3(1), dim3(64), 0, stream,
                           invH, g, pstore, gateflag, out);
    }
}

// Round 6
// 2760.433 us; speedup vs baseline: 1.5692x; 1.5692x over previous
//
#include <hip/hip_runtime.h>
#include <hip/hip_cooperative_groups.h>
#include <hip/hip_bf16.h>

namespace cg = cooperative_groups;

// OptFlow: forward-additive LK, B=16, k=4, 256x256, 20 iters.
// R3: single cooperative mega-kernel (1024 blocks x 256 thr, 4/CU), one
//     grid.sync()/iter; parallel 8x8 GJ inversion; p/gate in registers.
// R4: register template cache -> REGRESSION (scratch spill: 1.4GB writes,
//     3.2GB fetch, 4.3ms). Reverted.
// R5: hot loop back to R2 rolling temp loads (L1/L2-served, ~52 VGPR class).

#define B_   16
#define K_   4
#define H_   256
#define W_   256
#define HW_  (H_*W_)
#define ROWS_PER_BLOCK 16
#define NBLOCKS 1024          // = 16 batches x 64 bands; exactly 4 blocks/CU
#define NITER 20
#define TOL2 1.0e-6

#define MLO 0.99609375f
#define MHI 254.00390625f

// ---------------- ws layout (bytes) ----------------
#define WS_G       0          // [NITER][B_][8] double (g holds 2*J^T r)
#define WS_INVH    20480      // [B_][8][8] double
#define WS_HMPART  28672      // [NBLOCKS][36] double
#define WS_PSTORE  323584     // fallback only
#define WS_GATE    333824     // fallback only

// ===========================================================================
// cooperative mega-kernel
// ===========================================================================
__global__ __launch_bounds__(256, 4) void coop_kernel(
    const float* __restrict__ img, const float* __restrict__ temp,
    const float* __restrict__ init_param, float* __restrict__ out,
    double* __restrict__ g, double* __restrict__ invH,
    double* __restrict__ hmpart)
{
    cg::grid_group grid = cg::this_grid();
    const int bid = blockIdx.x;
    const int b = bid & 15;           // batch -> XCD b%8 pinned (L2 locality)
    const int band = bid >> 4;        // 0..63
    const int kc = band >> 4;
    const int ybase = (band & 15) << 4;
    const int tid = threadIdx.x;

    const float* tb = temp + (size_t)(b * K_ + kc) * HW_;
    const float* ib = img + (size_t)(b * K_ + kc) * HW_;

    const int x = tid;
    const int xmi = max(x - 1, 0), xpi = min(x + 1, W_ - 1);
    const float X = (float)x - 127.5f;
    const int lane = tid & 63, wave = tid >> 6;

    __shared__ double s_red36[4][36];
    __shared__ double s_redq[36][4];
    __shared__ double s_aug[8][16];
    __shared__ double s_invH[64];
    __shared__ double s_red8[4][8];
    __shared__ int s_pr;
    __shared__ double s_pivinv;

    // ---------------- phase P: Hm partials (0.5-scaled grads, exact) -------
    {
        float acc[36];
#pragma unroll
        for (int i = 0; i < 36; ++i) acc[i] = 0.0f;

        float tm = tb[max(ybase - 1, 0) * W_ + x];
        float t0 = tb[ybase * W_ + x];

#pragma unroll 4
        for (int r = 0; r < ROWS_PER_BLOCK; ++r) {
            const int y = ybase + r;
            const float Y = (float)y - 127.5f;
            const float tp = tb[min(y + 1, H_ - 1) * W_ + x];
            const float txm = tb[y * W_ + xmi];
            const float txp = tb[y * W_ + xpi];
            const float gx = 0.5f * (txp - txm);
            const float gy = 0.5f * (tp - tm);
            tm = t0; t0 = tp;

            const float s = fmaf(X, gx, Y * gy);
            float j[8];
            j[0] = X * gx; j[1] = Y * gx; j[2] = gx;
            j[3] = X * gy; j[4] = Y * gy; j[5] = gy;
            j[6] = -X * s; j[7] = -Y * s;
            int idx = 0;
#pragma unroll
            for (int a = 0; a < 8; ++a)
#pragma unroll
                for (int c = a; c < 8; ++c) {
                    acc[idx] = fmaf(j[a], j[c], acc[idx]);
                    ++idx;
                }
        }
#pragma unroll
        for (int i = 0; i < 36; ++i) {
            float v = acc[i];
            for (int off = 32; off > 0; off >>= 1) v += __shfl_down(v, off, 64);
            if (lane == 0) s_red36[wave][i] = (double)v;
        }
        __syncthreads();
        if (tid < 36)
            hmpart[(size_t)bid * 36 + tid] =
                s_red36[0][tid] + s_red36[1][tid] + s_red36[2][tid] + s_red36[3][tid];
    }

    grid.sync();  // #1: hmpart complete

    // ---------------- phase I: invert (blocks 0..15), zero g (16..31) ------
    if (bid < 16) {
        if (tid < 144) {
            const int c = tid >> 2, q = tid & 3;
            double s = 0.0;
            for (int m = 0; m < 16; ++m)
                s += hmpart[(size_t)((q * 16 + m) * 16 + b) * 36 + c];
            s_redq[c][q] = s;
        }
        __syncthreads();
        if (tid < 64) {
            const int j = tid >> 3, k2 = tid & 7;
            s_aug[j][8 + k2] = (j == k2) ? 1.0 : 0.0;
        }
        if (tid < 36) {
            const double sum = s_redq[tid][0] + s_redq[tid][1] + s_redq[tid][2] + s_redq[tid][3];
            int a = 0, base = 0;
            for (; a < 8; ++a) {
                const int next = base + (8 - a);
                if (tid < next) break;
                base = next;
            }
            const int cc = a + (tid - base);
            s_aug[a][cc] = sum;
            s_aug[cc][a] = sum;
        }
        __syncthreads();
        // parallel GJ with partial pivoting: 128 threads own (row, col)
        for (int piv = 0; piv < 8; ++piv) {
            if (tid == 0) {
                int pr = piv;
                double pv = fabs(s_aug[piv][piv]);
                for (int rr = piv + 1; rr < 8; ++rr) {
                    const double a2 = fabs(s_aug[rr][piv]);
                    if (a2 > pv) { pv = a2; pr = rr; }
                }
                s_pr = pr;
            }
            __syncthreads();
            const int pr = s_pr;
            if (pr != piv && tid < 16) {
                const double t1 = s_aug[piv][tid];
                s_aug[piv][tid] = s_aug[pr][tid];
                s_aug[pr][tid] = t1;
            }
            __syncthreads();
            if (tid == 0) s_pivinv = 1.0 / s_aug[piv][piv];
            __syncthreads();
            if (tid < 16) s_aug[piv][tid] *= s_pivinv;
            __syncthreads();
            const int r2 = tid >> 4, cc = tid & 15;
            double f = 0.0;
            if (tid < 128 && r2 != piv) f = s_aug[r2][piv];
            __syncthreads();
            if (tid < 128 && r2 != piv) s_aug[r2][cc] -= f * s_aug[piv][cc];
            __syncthreads();
        }
        if (tid < 64) invH[b * 64 + tid] = s_aug[tid >> 3][8 + (tid & 7)];
    } else if (bid < 32) {
        for (int t2 = tid; t2 < NITER * B_ * 8 / 16; t2 += 256)
            g[(bid - 16) * (NITER * B_ * 8 / 16) + t2] = 0.0;
    }

    grid.sync();  // #2: invH + zeroed g visible

    if (tid < 64) s_invH[tid] = invH[b * 64 + tid];
    // s_invH first read is after the in-loop grid.sync (block barrier incl.)

    float p[8];
#pragma unroll
    for (int j = 0; j < 8; ++j) p[j] = init_param[b * 8 + j];
    int gate = 1;  // ||dp0|| = sqrt(8) > TOL

    for (int it = 0; it < NITER; ++it) {
        if (gate) {
            const float a00 = 1.0f + p[0], a01 = p[1];
            const float a10 = p[3], a11 = 1.0f + p[4];
            const float a20 = p[6], a21 = p[7];
            const float a02c = p[2] + 127.5f;
            const float a12c = p[5] + 127.5f;
            const bool affine = (a20 == 0.0f) && (a21 == 0.0f);

            float acc0 = 0.f, acc1 = 0.f, acc2 = 0.f, acc3 = 0.f;
            float acc4 = 0.f, acc5 = 0.f, acc6 = 0.f, acc7 = 0.f;

            // rolling column registers for temp gradients (no spill: scalars)
            float tm = tb[max(ybase - 1, 0) * W_ + x];
            float t0 = tb[ybase * W_ + x];

#pragma unroll 4
            for (int r = 0; r < ROWS_PER_BLOCK; ++r) {
                const int y = ybase + r;
                const float Y = (float)y - 127.5f;
                float Xw, Yw;
                if (affine) {
                    Xw = fmaf(a00, X, fmaf(a01, Y, a02c));
                    Yw = fmaf(a10, X, fmaf(a11, Y, a12c));
                } else {
                    const float numx = fmaf(a00, X, fmaf(a01, Y, a02c - 127.5f));
                    const float numy = fmaf(a10, X, fmaf(a11, Y, a12c - 127.5f));
                    const float den = fmaf(a20, X, fmaf(a21, Y, 1.0f));
                    Xw = numx / den + 127.5f;
                    Yw = numy / den + 127.5f;
                }

                const float x0f = floorf(Xw), y0f = floorf(Yw);
                const float wx = Xw - x0f, wy = Yw - y0f;
                const int x0 = (int)x0f, y0 = (int)y0f;
                const int x1 = x0 + 1, y1 = y0 + 1;
                const int xc0 = min(max(x0, 0), W_ - 1), xc1 = min(max(x1, 0), W_ - 1);
                const int yc0 = min(max(y0, 0), H_ - 1), yc1 = min(max(y1, 0), H_ - 1);
                const bool vx0 = (unsigned)x0 < (unsigned)W_, vx1 = (unsigned)x1 < (unsigned)W_;
                const bool vy0 = (unsigned)y0 < (unsigned)H_, vy1 = (unsigned)y1 < (unsigned)H_;

                const int idx00 = yc0 * W_ + xc0;
                const int dxi = xc1 - xc0;
                const int dyi = (yc1 - yc0) * W_;
                float v00 = ib[idx00];
                float v01 = ib[idx00 + dxi];
                float v10 = ib[idx00 + dyi];
                float v11 = ib[idx00 + dyi + dxi];
                v00 = (vx0 && vy0) ? v00 : 0.0f;
                v01 = (vx1 && vy0) ? v01 : 0.0f;
                v10 = (vx0 && vy1) ? v10 : 0.0f;
                v11 = (vx1 && vy1) ? v11 : 0.0f;

                const float top = fmaf(wx, v01 - v00, v00);
                const float bot = fmaf(wx, v11 - v10, v10);
                const float Q = fmaf(wy, bot - top, top);

                const bool mask = (Xw > MLO) & (Xw < MHI) & (Yw > MLO) & (Yw < MHI);

                // temp value + raw (2x) gradients: 3 L1/L2-served loads/pixel
                const float tpv = tb[min(y + 1, H_ - 1) * W_ + x];
                const float txm = tb[y * W_ + xmi];
                const float txp = tb[y * W_ + xpi];
                const float Ft = t0;
                const float gx = txp - txm;   // 2x grads (exact), 0.5 in solve
                const float gy = tpv - tm;
                tm = t0; t0 = tpv;

                const float rr = Q - (mask ? Ft : 0.0f);
                const float rX = rr * X, rY = rr * Y;
                const float s = fmaf(X, gx, Y * gy);
                acc0 = fmaf(gx, rX, acc0);
                acc1 = fmaf(gx, rY, acc1);
                acc2 = fmaf(gx, rr, acc2);
                acc3 = fmaf(gy, rX, acc3);
                acc4 = fmaf(gy, rY, acc4);
                acc5 = fmaf(gy, rr, acc5);
                acc6 = fmaf(-s, rX, acc6);
                acc7 = fmaf(-s, rY, acc7);
            }

            float d8[8] = {acc0, acc1, acc2, acc3, acc4, acc5, acc6, acc7};
#pragma unroll
            for (int j = 0; j < 8; ++j) {
                float v = d8[j];
                for (int off = 32; off > 0; off >>= 1) v += __shfl_down(v, off, 64);
                if (lane == 0) s_red8[wave][j] = (double)v;
            }
            __syncthreads();
            if (tid < 8) {
                const double v = s_red8[0][tid] + s_red8[1][tid] + s_red8[2][tid] + s_red8[3][tid];
                unsafeAtomicAdd(&g[(size_t)(it * B_ + b) * 8 + tid], v);
            }
            __syncthreads();  // protect s_red8 reuse
        }

        grid.sync();  // g[it] complete everywhere

        if (gate) {   // replay solve (bit-identical across all blocks of batch b)
            const double* gp = g + (size_t)(it * B_ + b) * 8;
            double gv[8];
#pragma unroll
            for (int k2 = 0; k2 < 8; ++k2) gv[k2] = gp[k2];
            double nsq = 0.0;
#pragma unroll
            for (int j = 0; j < 6; ++j) {
                double s = 0.0;
#pragma unroll
                for (int k2 = 0; k2 < 8; ++k2) s += s_invH[j * 8 + k2] * gv[k2];
                const double dpj = 0.5 * s;  // exact compensation for 2x grads
                nsq += dpj * dpj;
                p[j] -= (float)dpj;
            }
            gate = (nsq > TOL2) ? 1 : 0;
        }
        // gate==0: dp=0, p frozen, gate stays 0 — matches reference recurrence
    }

    if (bid < 16) {  // b == bid here
        if (tid < 8) out[b * 8 + tid] = p[tid];
        if (tid < 9) {
            float v = (tid < 8) ? p[tid] : 0.0f;
            if (tid == 0 || tid == 4 || tid == 8) v += 1.0f;
            out[B_ * 8 + b * 9 + tid] = v;
        }
    }
}

// ===========================================================================
// fallback chain (R2 kernels, verbatim — proven passing) — used only if the
// cooperative launch is rejected.
// ===========================================================================
__global__ __launch_bounds__(256, 2) void prep_kernel(const float* __restrict__ temp,
                                                      double* __restrict__ hmpart) {
    const int bid = blockIdx.x;
    const int b = bid & 15;
    const int strip = bid >> 4;
    const int tid = threadIdx.x;
    const int kc = strip >> 4;
    const int ybase = (strip & 15) << 4;
    const float* tb = temp + (size_t)(b * K_ + kc) * HW_;

    const int x = tid;
    const int xm = max(x - 1, 0), xp = min(x + 1, W_ - 1);
    const float X = (float)x - 127.5f;

    float acc[36];
#pragma unroll
    for (int i = 0; i < 36; ++i) acc[i] = 0.0f;

    float tm = tb[max(ybase - 1, 0) * W_ + x];
    float t0 = tb[ybase * W_ + x];

#pragma unroll 4
    for (int r = 0; r < ROWS_PER_BLOCK; ++r) {
        const int y = ybase + r;
        const float Y = (float)y - 127.5f;
        const float tp = tb[min(y + 1, H_ - 1) * W_ + x];
        const float txm = tb[y * W_ + xm];
        const float txp = tb[y * W_ + xp];
        const float gx = 0.5f * (txp - txm);
        const float gy = 0.5f * (tp - tm);
        tm = t0; t0 = tp;

        const float s = fmaf(X, gx, Y * gy);
        float j[8];
        j[0] = X * gx; j[1] = Y * gx; j[2] = gx;
        j[3] = X * gy; j[4] = Y * gy; j[5] = gy;
        j[6] = -X * s; j[7] = -Y * s;
        int idx = 0;
#pragma unroll
        for (int a = 0; a < 8; ++a)
#pragma unroll
            for (int c = a; c < 8; ++c) {
                acc[idx] = fmaf(j[a], j[c], acc[idx]);
                ++idx;
            }
    }

    __shared__ double red[4][36];
    const int lane = tid & 63, wave = tid >> 6;
#pragma unroll
    for (int i = 0; i < 36; ++i) {
        double v = (double)acc[i];
        for (int off = 32; off > 0; off >>= 1) v += __shfl_down(v, off, 64);
        if (lane == 0) red[wave][i] = v;
    }
    __syncthreads();
    if (tid < 36)
        hmpart[(size_t)bid * 36 + tid] =
            red[0][tid] + red[1][tid] + red[2][tid] + red[3][tid];
}

__global__ __launch_bounds__(256) void solveh_kernel(const double* __restrict__ hmpart,
                                                     const float* __restrict__ init_param,
                                                     double* __restrict__ invH,
                                                     double* __restrict__ g,
                                                     float* __restrict__ pstore) {
    __shared__ double aug[B_][8][16];
    const int tid = threadIdx.x;

    for (int t = tid; t < NITER * B_ * 8; t += 256) g[t] = 0.0;
    for (int t = tid; t < B_ * 8; t += 256) pstore[t] = init_param[t];

    for (int t = tid; t < B_ * 64; t += 256) {
        const int b = t >> 6, j = (t >> 3) & 7, k = t & 7;
        aug[b][j][8 + k] = (j == k) ? 1.0 : 0.0;
    }
    for (int t = tid; t < B_ * 36; t += 256) {
        const int b = t / 36, c = t % 36;
        double sum = 0.0;
        for (int s = 0; s < 64; ++s) sum += hmpart[(size_t)(s * 16 + b) * 36 + c];
        int a = 0, base = 0;
        for (; a < 8; ++a) {
            const int next = base + (8 - a);
            if (c < next) break;
            base = next;
        }
        const int cc = a + (c - base);
        aug[b][a][cc] = sum;
        aug[b][cc][a] = sum;
    }
    __syncthreads();

    if (tid < B_) {
        double (*A)[16] = aug[tid];
        for (int piv = 0; piv < 8; ++piv) {
            int pr = piv;
            double pv = fabs(A[piv][piv]);
            for (int rr = piv + 1; rr < 8; ++rr) {
                const double a2 = fabs(A[rr][piv]);
                if (a2 > pv) { pv = a2; pr = rr; }
            }
            if (pr != piv)
                for (int c = 0; c < 16; ++c) {
                    const double tmp = A[piv][c]; A[piv][c] = A[pr][c]; A[pr][c] = tmp;
                }
            const double inv = 1.0 / A[piv][piv];
            for (int c = 0; c < 16; ++c) A[piv][c] *= inv;
            for (int rr = 0; rr < 8; ++rr) {
                if (rr == piv) continue;
                const double f = A[rr][piv];
                for (int c = 0; c < 16; ++c) A[rr][c] -= f * A[piv][c];
            }
        }
        for (int j = 0; j < 8; ++j)
            for (int k = 0; k < 8; ++k)
                invH[tid * 64 + j * 8 + k] = A[j][8 + k];
    }
}

__device__ __forceinline__ void solve_step(const double* __restrict__ invHb,
                                           const double* __restrict__ gprev,
                                           const float* __restrict__ pprev,
                                           int gate_prev, float* p, int* gate_out) {
    double dp[8];
#pragma unroll
    for (int j = 0; j < 8; ++j) dp[j] = 0.0;
    if (gate_prev) {
#pragma unroll
        for (int j = 0; j < 6; ++j) {
            double s = 0.0;
#pragma unroll
            for (int k = 0; k < 8; ++k) s += invHb[j * 8 + k] * gprev[k];
            dp[j] = 0.5 * s;
        }
    }
    double nsq = 0.0;
#pragma unroll
    for (int j = 0; j < 8; ++j) nsq += dp[j] * dp[j];
    *gate_out = (nsq > TOL2) ? 1 : 0;
#pragma unroll
    for (int j = 0; j < 8; ++j) p[j] = pprev[j] - (float)dp[j];
}

__global__ __launch_bounds__(256, 4) void iter_kernel(const float* __restrict__ img,
                                                      const float* __restrict__ temp,
                                                      const float* __restrict__ init_param,
                                                      const double* __restrict__ invH,
                                                      double* __restrict__ g,
                                                      float* __restrict__ pstore,
                                                      int* __restrict__ gateflag,
                                                      int iter) {
    const int bid = blockIdx.x;
    const int b = bid & 15;
    const int strip = bid >> 4;
    const int tid = threadIdx.x;

    float p[8];
    int gate;
    if (iter == 0) {
#pragma unroll
        for (int j = 0; j < 8; ++j) p[j] = init_param[b * 8 + j];
        gate = 1;
    } else {
        solve_step(invH + b * 64, g + (size_t)((iter - 1) * B_ + b) * 8,
                   pstore + (size_t)((iter - 1) * B_ + b) * 8,
                   gateflag[(iter - 1) * B_ + b], p, &gate);
    }
    if (tid < 8) pstore[(size_t)(iter * B_ + b) * 8 + tid] = p[tid];
    if (tid == 0) gateflag[iter * B_ + b] = gate;
    if (!gate) return;

    const int kc = strip >> 4;
    const int ybase = (strip & 15) << 4;
    const float* ib = img + (size_t)(b * K_ + kc) * HW_;
    const float* tb = temp + (size_t)(b * K_ + kc) * HW_;

    const float a00 = 1.0f + p[0], a01 = p[1];
    const float a10 = p[3], a11 = 1.0f + p[4];
    const float a20 = p[6], a21 = p[7];
    const float a02c = p[2] + 127.5f;
    const float a12c = p[5] + 127.5f;
    const bool affine = (a20 == 0.0f) && (a21 == 0.0f);

    const int x = tid;
    const int xm = max(x - 1, 0), xp = min(x + 1, W_ - 1);
    const float X = (float)x - 127.5f;

    float acc0 = 0.f, acc1 = 0.f, acc2 = 0.f, acc3 = 0.f;
    float acc4 = 0.f, acc5 = 0.f, acc6 = 0.f, acc7 = 0.f;

    float tm = tb[max(ybase - 1, 0) * W_ + x];
    float t0 = tb[ybase * W_ + x];

#pragma unroll 4
    for (int r = 0; r < ROWS_PER_BLOCK; ++r) {
        const int y = ybase + r;
        const float Y = (float)y - 127.5f;
        float Xw, Yw;
        if (affine) {
            Xw = fmaf(a00, X, fmaf(a01, Y, a02c));
            Yw = fmaf(a10, X, fmaf(a11, Y, a12c));
        } else {
            const float numx = fmaf(a00, X, fmaf(a01, Y, a02c - 127.5f));
            const float numy = fmaf(a10, X, fmaf(a11, Y, a12c - 127.5f));
            const float den = fmaf(a20, X, fmaf(a21, Y, 1.0f));
            Xw = numx / den + 127.5f;
            Yw = numy / den + 127.5f;
        }

        const float x0f = floorf(Xw), y0f = floorf(Yw);
        const float wx = Xw - x0f, wy = Yw - y0f;
        const int x0 = (int)x0f, y0 = (int)y0f;
        const int x1 = x0 + 1, y1 = y0 + 1;
        const int xc0 = min(max(x0, 0), W_ - 1), xc1 = min(max(x1, 0), W_ - 1);
        const int yc0 = min(max(y0, 0), H_ - 1), yc1 = min(max(y1, 0), H_ - 1);
        const bool vx0 = (unsigned)x0 < (unsigned)W_, vx1 = (unsigned)x1 < (unsigned)W_;
        const bool vy0 = (unsigned)y0 < (unsigned)H_, vy1 = (unsigned)y1 < (unsigned)H_;

        const int idx00 = yc0 * W_ + xc0;
        const int dxi = xc1 - xc0;
        const int dyi = (yc1 - yc0) * W_;
        float v00 = ib[idx00];
        float v01 = ib[idx00 + dxi];
        float v10 = ib[idx00 + dyi];
        float v11 = ib[idx00 + dyi + dxi];
        v00 = (vx0 && vy0) ? v00 : 0.0f;
        v01 = (vx1 && vy0) ? v01 : 0.0f;
        v10 = (vx0 && vy1) ? v10 : 0.0f;
        v11 = (vx1 && vy1) ? v11 : 0.0f;

        const float top = fmaf(wx, v01 - v00, v00);
        const float bot = fmaf(wx, v11 - v10, v10);
        const float Q = fmaf(wy, bot - top, top);

        const bool mask = (Xw > MLO) & (Xw < MHI) & (Yw > MLO) & (Yw < MHI);

        const float tpv = tb[min(y + 1, H_ - 1) * W_ + x];
        const float txm = tb[y * W_ + xm];
        const float txp = tb[y * W_ + xp];
        const float Ft = t0;
        const float gx = txp - txm;
        const float gy = tpv - tm;
        tm = t0; t0 = tpv;

        const float rr = Q - (mask ? Ft : 0.0f);
        const float rX = rr * X, rY = rr * Y;
        const float s = fmaf(X, gx, Y * gy);
        acc0 = fmaf(gx, rX, acc0);
        acc1 = fmaf(gx, rY, acc1);
        acc2 = fmaf(gx, rr, acc2);
        acc3 = fmaf(gy, rX, acc3);
        acc4 = fmaf(gy, rY, acc4);
        acc5 = fmaf(gy, rr, acc5);
        acc6 = fmaf(-s, rX, acc6);
        acc7 = fmaf(-s, rY, acc7);
    }

    __shared__ double red[4][8];
    const int lane = tid & 63, wave = tid >> 6;
    float d[8] = {acc0, acc1, acc2, acc3, acc4, acc5, acc6, acc7};
#pragma unroll
    for (int j = 0; j < 8; ++j) {
        float v = d[j];
        for (int off = 32; off > 0; off >>= 1) v += __shfl_down(v, off, 64);
        if (lane == 0) red[wave][j] = (double)v;
    }
    __syncthreads();
    if (tid < 8) {
        const double v = red[0][tid] + red[1][tid] + red[2][tid] + red[3][tid];
        unsafeAtomicAdd(&g[(size_t)(iter * B_ + b) * 8 + tid], v);
    }
}

__global__ void finish_kernel(const double* __restrict__ invH,
                              const double* __restrict__ g,
                              const float* __restrict__ pstore,
                              const int* __restrict__ gateflag,
                              float* __restrict__ out) {
    const int tid = threadIdx.x;
    if (tid < B_) {
        const int b = tid;
        float pf[8];
        int gate_dummy;
        solve_step(invH + b * 64, g + (size_t)((NITER - 1) * B_ + b) * 8,
                   pstore + (size_t)((NITER - 1) * B_ + b) * 8,
                   gateflag[(NITER - 1) * B_ + b], pf, &gate_dummy);
        for (int j = 0; j < 8; ++j) out[b * 8 + j] = pf[j];
        float* Hout = out + B_ * 8 + b * 9;
        for (int idx = 0; idx < 9; ++idx) {
            float v = (idx < 8) ? pf[idx] : 0.0f;
            if (idx == 0 || idx == 4 || idx == 8) v += 1.0f;
            Hout[idx] = v;
        }
    }
}

extern "C" void kernel_launch(void* const* d_in, const int* in_sizes, int n_in,
                              void* d_out, int out_size, void* d_ws, size_t ws_size,
                              hipStream_t stream) {
    (void)in_sizes; (void)n_in; (void)out_size; (void)ws_size;
    const float* img = (const float*)d_in[0];
    const float* temp = (const float*)d_in[1];
    const float* init_param = (const float*)d_in[2];

    float* out = (float*)d_out;
    char* ws = (char*)d_ws;
    double* g = (double*)(ws + WS_G);
    double* invH = (double*)(ws + WS_INVH);
    double* hmpart = (double*)(ws + WS_HMPART);
    float* pstore = (float*)(ws + WS_PSTORE);
    int* gateflag = (int*)(ws + WS_GATE);

    void* kargs[] = {(void*)&img, (void*)&temp, (void*)&init_param,
                     (void*)&out, (void*)&g, (void*)&invH, (void*)&hmpart};
    hipError_t err = hipLaunchCooperativeKernel((const void*)coop_kernel,
                                                dim3(NBLOCKS), dim3(256),
                                                kargs, 0, stream);
    if (err != hipSuccess) {
        // fallback: proven R2 multi-kernel chain
        hipLaunchKernelGGL(prep_kernel, dim3(NBLOCKS), dim3(256), 0, stream, temp, hmpart);
        hipLaunchKernelGGL(solveh_kernel, dim3(1), dim3(256), 0, stream,
                           hmpart, init_param, invH, g, pstore);
        for (int i = 0; i < NITER; ++i) {
            hipLaunchKernelGGL(iter_kernel, dim3(NBLOCKS), dim3(256), 0, stream,
                               img, temp, init_param, invH, g, pstore, gateflag, i);
        }
        hipLaunchKernelGGL(finish_kernel, dim3(1), dim3(64), 0, stream,
                           invH, g, pstore, gateflag, out);
    }
}

// Round 8
// 958.748 us; speedup vs baseline: 4.5180x; 2.8792x over previous
//
#include <hip/hip_runtime.h>
#include <hip/hip_cooperative_groups.h>
#include <hip/hip_bf16.h>

// OptFlow: forward-additive LK, B=16, k=4, 256x256, 20 iters.
// R5 post-mortem: grid.sync() costs ~115us each (1024-wg single-counter far
// atomics + global fence) -> 2.7ms. R6/R7: per-BATCH 64-wg flag barriers (16
// independent counters, disjoint cachelines), no grid.sync. 3 graph nodes:
// prep_zero -> solveh_par (parallel GJ) -> persistent coop kernel.
// (R7 = R6 resubmitted after GPU timeout; correctness re-audited, no change.)

#define B_   16
#define K_   4
#define H_   256
#define W_   256
#define HW_  (H_*W_)
#define ROWS_PER_BLOCK 16
#define NBLOCKS 1024          // 16 batches x 64 bands; exactly 4 blocks/CU
#define NITER 20
#define TOL2 1.0e-6

#define MLO 0.99609375f
#define MHI 254.00390625f

#define CNT_STRIDE 32         // ints (128 B): one L2 line per (iter,batch) slot

// ---------------- ws layout (bytes) ----------------
// g      : [NITER][B_][8] double @ 0       (20480)   g holds 2*(J^T r)
// invH   : [B_][8][8]    double @ 20480   (8192)
// hmpart : [NBLOCKS][36] double @ 28672   (294912) -> 323584
// cnt    : [NITER][B_][CNT_STRIDE] int @ 323584 (40960) -> 364544
// pstore : [NITER][B_][8] float @ 364544  (10240)  (fallback only)
// gate   : [NITER][B_]   int    @ 374784  (1280)   (fallback only)
#define WS_G       0
#define WS_INVH    20480
#define WS_HMPART  28672
#define WS_CNT     323584
#define WS_PSTORE  364544
#define WS_GATE    374784

// ===========================================================================
// node 1: zero g+cnt, compute per-block Hm partials
// ===========================================================================
__global__ __launch_bounds__(256, 2) void prep_zero_kernel(const float* __restrict__ temp,
                                                           double* __restrict__ hmpart,
                                                           double* __restrict__ g,
                                                           int* __restrict__ cnt) {
    const int bid = blockIdx.x;
    const int tid = threadIdx.x;

    // zero g (5120 ints) + cnt (10240 ints): first 60 blocks, 1 int/thread
    {
        const int i = bid * 256 + tid;
        if (i < 5120) ((int*)g)[i] = 0;
        else if (i < 15360) cnt[i - 5120] = 0;
    }

    const int b = bid & 15;
    const int strip = bid >> 4;
    const int kc = strip >> 4;
    const int ybase = (strip & 15) << 4;
    const float* tb = temp + (size_t)(b * K_ + kc) * HW_;

    const int x = tid;
    const int xm = max(x - 1, 0), xp = min(x + 1, W_ - 1);
    const float X = (float)x - 127.5f;

    float acc[36];
#pragma unroll
    for (int i = 0; i < 36; ++i) acc[i] = 0.0f;

    float tm = tb[max(ybase - 1, 0) * W_ + x];
    float t0 = tb[ybase * W_ + x];

#pragma unroll 4
    for (int r = 0; r < ROWS_PER_BLOCK; ++r) {
        const int y = ybase + r;
        const float Y = (float)y - 127.5f;
        const float tp = tb[min(y + 1, H_ - 1) * W_ + x];
        const float txm = tb[y * W_ + xm];
        const float txp = tb[y * W_ + xp];
        const float gx = 0.5f * (txp - txm);
        const float gy = 0.5f * (tp - tm);
        tm = t0; t0 = tp;

        const float s = fmaf(X, gx, Y * gy);
        float j[8];
        j[0] = X * gx; j[1] = Y * gx; j[2] = gx;
        j[3] = X * gy; j[4] = Y * gy; j[5] = gy;
        j[6] = -X * s; j[7] = -Y * s;
        int idx = 0;
#pragma unroll
        for (int a = 0; a < 8; ++a)
#pragma unroll
            for (int c = a; c < 8; ++c) {
                acc[idx] = fmaf(j[a], j[c], acc[idx]);
                ++idx;
            }
    }

    __shared__ double red[4][36];
    const int lane = tid & 63, wave = tid >> 6;
#pragma unroll
    for (int i = 0; i < 36; ++i) {
        float v = acc[i];
        for (int off = 32; off > 0; off >>= 1) v += __shfl_down(v, off, 64);
        if (lane == 0) red[wave][i] = (double)v;
    }
    __syncthreads();
    if (tid < 36)
        hmpart[(size_t)bid * 36 + tid] =
            red[0][tid] + red[1][tid] + red[2][tid] + red[3][tid];
}

// ===========================================================================
// node 2: reduce Hm partials + parallel 8x8 GJ inversion, 1 block/batch.
// Also inits pstore[0] for the fallback path.
// ===========================================================================
__global__ __launch_bounds__(256) void solveh_par_kernel(const double* __restrict__ hmpart,
                                                         const float* __restrict__ init_param,
                                                         double* __restrict__ invH,
                                                         float* __restrict__ pstore) {
    const int b = blockIdx.x;
    const int tid = threadIdx.x;

    __shared__ double s_redq[36][4];
    __shared__ double s_aug[8][16];
    __shared__ int s_pr;
    __shared__ double s_pivinv;

    if (b == 0 && tid < B_ * 8) pstore[tid] = init_param[tid];

    if (tid < 144) {
        const int c = tid >> 2, q = tid & 3;
        double s = 0.0;
        for (int m = 0; m < 16; ++m)
            s += hmpart[(size_t)((q * 16 + m) * 16 + b) * 36 + c];
        s_redq[c][q] = s;
    }
    __syncthreads();
    if (tid < 64) {
        const int j = tid >> 3, k2 = tid & 7;
        s_aug[j][8 + k2] = (j == k2) ? 1.0 : 0.0;
    }
    if (tid < 36) {
        const double sum = s_redq[tid][0] + s_redq[tid][1] + s_redq[tid][2] + s_redq[tid][3];
        int a = 0, base = 0;
        for (; a < 8; ++a) {
            const int next = base + (8 - a);
            if (tid < next) break;
            base = next;
        }
        const int cc = a + (tid - base);
        s_aug[a][cc] = sum;
        s_aug[cc][a] = sum;
    }
    __syncthreads();
    for (int piv = 0; piv < 8; ++piv) {
        if (tid == 0) {
            int pr = piv;
            double pv = fabs(s_aug[piv][piv]);
            for (int rr = piv + 1; rr < 8; ++rr) {
                const double a2 = fabs(s_aug[rr][piv]);
                if (a2 > pv) { pv = a2; pr = rr; }
            }
            s_pr = pr;
        }
        __syncthreads();
        const int pr = s_pr;
        if (pr != piv && tid < 16) {
            const double t1 = s_aug[piv][tid];
            s_aug[piv][tid] = s_aug[pr][tid];
            s_aug[pr][tid] = t1;
        }
        __syncthreads();
        if (tid == 0) s_pivinv = 1.0 / s_aug[piv][piv];
        __syncthreads();
        if (tid < 16) s_aug[piv][tid] *= s_pivinv;
        __syncthreads();
        const int r2 = tid >> 4, cc = tid & 15;
        double f = 0.0;
        if (tid < 128 && r2 != piv) f = s_aug[r2][piv];
        __syncthreads();
        if (tid < 128 && r2 != piv) s_aug[r2][cc] -= f * s_aug[piv][cc];
        __syncthreads();
    }
    if (tid < 64) invH[b * 64 + tid] = s_aug[tid >> 3][8 + (tid & 7)];
}

// ===========================================================================
// node 3: persistent iteration kernel (cooperative launch for co-residency
// guarantee only — NO grid.sync; per-batch 64-block flag barriers).
// ===========================================================================
__global__ __launch_bounds__(256, 4) void persist_kernel(
    const float* __restrict__ img, const float* __restrict__ temp,
    const float* __restrict__ init_param, float* __restrict__ out,
    double* __restrict__ g, const double* __restrict__ invH,
    int* __restrict__ cnt)
{
    const int bid = blockIdx.x;
    const int b = bid & 15;           // batch -> XCD b%8 pinned (L2 locality)
    const int band = bid >> 4;        // 0..63
    const int kc = band >> 4;
    const int ybase = (band & 15) << 4;
    const int tid = threadIdx.x;

    const float* tb = temp + (size_t)(b * K_ + kc) * HW_;
    const float* ib = img + (size_t)(b * K_ + kc) * HW_;

    const int x = tid;
    const int xmi = max(x - 1, 0), xpi = min(x + 1, W_ - 1);
    const float X = (float)x - 127.5f;
    const int lane = tid & 63, wave = tid >> 6;

    __shared__ double s_invH[64];
    __shared__ double s_red8[4][8];
    __shared__ double s_g[8];

    if (tid < 64) s_invH[tid] = invH[b * 64 + tid];
    __syncthreads();

    float p[8];
#pragma unroll
    for (int j = 0; j < 8; ++j) p[j] = init_param[b * 8 + j];
    int gate = 1;  // ||dp0|| = sqrt(8) > TOL

    for (int it = 0; it < NITER; ++it) {
        // ---- compute g[it][b] contribution (identical numerics to R5) ----
        {
            const float a00 = 1.0f + p[0], a01 = p[1];
            const float a10 = p[3], a11 = 1.0f + p[4];
            const float a20 = p[6], a21 = p[7];
            const float a02c = p[2] + 127.5f;
            const float a12c = p[5] + 127.5f;
            const bool affine = (a20 == 0.0f) && (a21 == 0.0f);

            float acc0 = 0.f, acc1 = 0.f, acc2 = 0.f, acc3 = 0.f;
            float acc4 = 0.f, acc5 = 0.f, acc6 = 0.f, acc7 = 0.f;

            float tm = tb[max(ybase - 1, 0) * W_ + x];
            float t0 = tb[ybase * W_ + x];

#pragma unroll 4
            for (int r = 0; r < ROWS_PER_BLOCK; ++r) {
                const int y = ybase + r;
                const float Y = (float)y - 127.5f;
                float Xw, Yw;
                if (affine) {
                    Xw = fmaf(a00, X, fmaf(a01, Y, a02c));
                    Yw = fmaf(a10, X, fmaf(a11, Y, a12c));
                } else {
                    const float numx = fmaf(a00, X, fmaf(a01, Y, a02c - 127.5f));
                    const float numy = fmaf(a10, X, fmaf(a11, Y, a12c - 127.5f));
                    const float den = fmaf(a20, X, fmaf(a21, Y, 1.0f));
                    Xw = numx / den + 127.5f;
                    Yw = numy / den + 127.5f;
                }

                const float x0f = floorf(Xw), y0f = floorf(Yw);
                const float wx = Xw - x0f, wy = Yw - y0f;
                const int x0 = (int)x0f, y0 = (int)y0f;
                const int x1 = x0 + 1, y1 = y0 + 1;
                const int xc0 = min(max(x0, 0), W_ - 1), xc1 = min(max(x1, 0), W_ - 1);
                const int yc0 = min(max(y0, 0), H_ - 1), yc1 = min(max(y1, 0), H_ - 1);
                const bool vx0 = (unsigned)x0 < (unsigned)W_, vx1 = (unsigned)x1 < (unsigned)W_;
                const bool vy0 = (unsigned)y0 < (unsigned)H_, vy1 = (unsigned)y1 < (unsigned)H_;

                const int idx00 = yc0 * W_ + xc0;
                const int dxi = xc1 - xc0;
                const int dyi = (yc1 - yc0) * W_;
                float v00 = ib[idx00];
                float v01 = ib[idx00 + dxi];
                float v10 = ib[idx00 + dyi];
                float v11 = ib[idx00 + dyi + dxi];
                v00 = (vx0 && vy0) ? v00 : 0.0f;
                v01 = (vx1 && vy0) ? v01 : 0.0f;
                v10 = (vx0 && vy1) ? v10 : 0.0f;
                v11 = (vx1 && vy1) ? v11 : 0.0f;

                const float top = fmaf(wx, v01 - v00, v00);
                const float bot = fmaf(wx, v11 - v10, v10);
                const float Q = fmaf(wy, bot - top, top);

                const bool mask = (Xw > MLO) & (Xw < MHI) & (Yw > MLO) & (Yw < MHI);

                const float tpv = tb[min(y + 1, H_ - 1) * W_ + x];
                const float txm = tb[y * W_ + xmi];
                const float txp = tb[y * W_ + xpi];
                const float Ft = t0;
                const float gx = txp - txm;   // 2x grads (exact), 0.5 in solve
                const float gy = tpv - tm;
                tm = t0; t0 = tpv;

                const float rr = Q - (mask ? Ft : 0.0f);
                const float rX = rr * X, rY = rr * Y;
                const float s = fmaf(X, gx, Y * gy);
                acc0 = fmaf(gx, rX, acc0);
                acc1 = fmaf(gx, rY, acc1);
                acc2 = fmaf(gx, rr, acc2);
                acc3 = fmaf(gy, rX, acc3);
                acc4 = fmaf(gy, rY, acc4);
                acc5 = fmaf(gy, rr, acc5);
                acc6 = fmaf(-s, rX, acc6);
                acc7 = fmaf(-s, rY, acc7);
            }

            float d8[8] = {acc0, acc1, acc2, acc3, acc4, acc5, acc6, acc7};
#pragma unroll
            for (int j = 0; j < 8; ++j) {
                float v = d8[j];
                for (int off = 32; off > 0; off >>= 1) v += __shfl_down(v, off, 64);
                if (lane == 0) s_red8[wave][j] = (double)v;
            }
            __syncthreads();
            if (tid < 8) {   // wave 0 issues the 8 device-scope f64 atomics
                const double v = s_red8[0][tid] + s_red8[1][tid] + s_red8[2][tid] + s_red8[3][tid];
                unsafeAtomicAdd(&g[(size_t)(it * B_ + b) * 8 + tid], v);
            }
        }

        // ---- per-batch barrier: 64 blocks on one dedicated cacheline ----
        int* c = cnt + (it * B_ + b) * CNT_STRIDE;
        if (tid == 0) {
            __threadfence();  // g-atomics (same wave) complete before arrival
            __hip_atomic_fetch_add(c, 1, __ATOMIC_RELAXED, __HIP_MEMORY_SCOPE_AGENT);
            while (__hip_atomic_load(c, __ATOMIC_RELAXED, __HIP_MEMORY_SCOPE_AGENT) < 64)
                __builtin_amdgcn_s_sleep(2);
            __threadfence();
        }
        __syncthreads();

        // ---- read final g (agent-scope loads bypass stale caches) ----
        if (tid < 8)
            s_g[tid] = __hip_atomic_load(&g[(size_t)(it * B_ + b) * 8 + tid],
                                         __ATOMIC_RELAXED, __HIP_MEMORY_SCOPE_AGENT);
        __syncthreads();

        // ---- solve (bit-identical across the batch's 64 blocks) ----
        {
            double nsq = 0.0;
#pragma unroll
            for (int j = 0; j < 6; ++j) {
                double s = 0.0;
#pragma unroll
                for (int k2 = 0; k2 < 8; ++k2) s += s_invH[j * 8 + k2] * s_g[k2];
                const double dpj = 0.5 * s;  // exact compensation for 2x grads
                nsq += dpj * dpj;
                p[j] -= (float)dpj;
            }
            gate = (nsq > TOL2) ? 1 : 0;
        }
        if (!gate) break;  // whole batch breaks together; its counters unused after
    }

    if (band == 0) {  // bids 0..15, b == bid
        if (tid < 8) out[b * 8 + tid] = p[tid];
        if (tid < 9) {
            float v = (tid < 8) ? p[tid] : 0.0f;
            if (tid == 0 || tid == 4 || tid == 8) v += 1.0f;
            out[B_ * 8 + b * 9 + tid] = v;
        }
    }
}

// ===========================================================================
// fallback chain (R2/R5 proven) — only if cooperative launch is rejected.
// ===========================================================================
__device__ __forceinline__ void solve_step(const double* __restrict__ invHb,
                                           const double* __restrict__ gprev,
                                           const float* __restrict__ pprev,
                                           int gate_prev, float* p, int* gate_out) {
    double dp[8];
#pragma unroll
    for (int j = 0; j < 8; ++j) dp[j] = 0.0;
    if (gate_prev) {
#pragma unroll
        for (int j = 0; j < 6; ++j) {
            double s = 0.0;
#pragma unroll
            for (int k = 0; k < 8; ++k) s += invHb[j * 8 + k] * gprev[k];
            dp[j] = 0.5 * s;
        }
    }
    double nsq = 0.0;
#pragma unroll
    for (int j = 0; j < 8; ++j) nsq += dp[j] * dp[j];
    *gate_out = (nsq > TOL2) ? 1 : 0;
#pragma unroll
    for (int j = 0; j < 8; ++j) p[j] = pprev[j] - (float)dp[j];
}

__global__ __launch_bounds__(256, 4) void iter_kernel(const float* __restrict__ img,
                                                      const float* __restrict__ temp,
                                                      const float* __restrict__ init_param,
                                                      const double* __restrict__ invH,
                                                      double* __restrict__ g,
                                                      float* __restrict__ pstore,
                                                      int* __restrict__ gateflag,
                                                      int iter) {
    const int bid = blockIdx.x;
    const int b = bid & 15;
    const int strip = bid >> 4;
    const int tid = threadIdx.x;

    float p[8];
    int gate;
    if (iter == 0) {
#pragma unroll
        for (int j = 0; j < 8; ++j) p[j] = init_param[b * 8 + j];
        gate = 1;
    } else {
        solve_step(invH + b * 64, g + (size_t)((iter - 1) * B_ + b) * 8,
                   pstore + (size_t)((iter - 1) * B_ + b) * 8,
                   gateflag[(iter - 1) * B_ + b], p, &gate);
    }
    if (tid < 8) pstore[(size_t)(iter * B_ + b) * 8 + tid] = p[tid];
    if (tid == 0) gateflag[iter * B_ + b] = gate;
    if (!gate) return;

    const int kc = strip >> 4;
    const int ybase = (strip & 15) << 4;
    const float* ib = img + (size_t)(b * K_ + kc) * HW_;
    const float* tb = temp + (size_t)(b * K_ + kc) * HW_;

    const float a00 = 1.0f + p[0], a01 = p[1];
    const float a10 = p[3], a11 = 1.0f + p[4];
    const float a20 = p[6], a21 = p[7];
    const float a02c = p[2] + 127.5f;
    const float a12c = p[5] + 127.5f;
    const bool affine = (a20 == 0.0f) && (a21 == 0.0f);

    const int x = tid;
    const int xm = max(x - 1, 0), xp = min(x + 1, W_ - 1);
    const float X = (float)x - 127.5f;

    float acc0 = 0.f, acc1 = 0.f, acc2 = 0.f, acc3 = 0.f;
    float acc4 = 0.f, acc5 = 0.f, acc6 = 0.f, acc7 = 0.f;

    float tm = tb[max(ybase - 1, 0) * W_ + x];
    float t0 = tb[ybase * W_ + x];

#pragma unroll 4
    for (int r = 0; r < ROWS_PER_BLOCK; ++r) {
        const int y = ybase + r;
        const float Y = (float)y - 127.5f;
        float Xw, Yw;
        if (affine) {
            Xw = fmaf(a00, X, fmaf(a01, Y, a02c));
            Yw = fmaf(a10, X, fmaf(a11, Y, a12c));
        } else {
            const float numx = fmaf(a00, X, fmaf(a01, Y, a02c - 127.5f));
            const float numy = fmaf(a10, X, fmaf(a11, Y, a12c - 127.5f));
            const float den = fmaf(a20, X, fmaf(a21, Y, 1.0f));
            Xw = numx / den + 127.5f;
            Yw = numy / den + 127.5f;
        }

        const float x0f = floorf(Xw), y0f = floorf(Yw);
        const float wx = Xw - x0f, wy = Yw - y0f;
        const int x0 = (int)x0f, y0 = (int)y0f;
        const int x1 = x0 + 1, y1 = y0 + 1;
        const int xc0 = min(max(x0, 0), W_ - 1), xc1 = min(max(x1, 0), W_ - 1);
        const int yc0 = min(max(y0, 0), H_ - 1), yc1 = min(max(y1, 0), H_ - 1);
        const bool vx0 = (unsigned)x0 < (unsigned)W_, vx1 = (unsigned)x1 < (unsigned)W_;
        const bool vy0 = (unsigned)y0 < (unsigned)H_, vy1 = (unsigned)y1 < (unsigned)H_;

        const int idx00 = yc0 * W_ + xc0;
        const int dxi = xc1 - xc0;
        const int dyi = (yc1 - yc0) * W_;
        float v00 = ib[idx00];
        float v01 = ib[idx00 + dxi];
        float v10 = ib[idx00 + dyi];
        float v11 = ib[idx00 + dyi + dxi];
        v00 = (vx0 && vy0) ? v00 : 0.0f;
        v01 = (vx1 && vy0) ? v01 : 0.0f;
        v10 = (vx0 && vy1) ? v10 : 0.0f;
        v11 = (vx1 && vy1) ? v11 : 0.0f;

        const float top = fmaf(wx, v01 - v00, v00);
        const float bot = fmaf(wx, v11 - v10, v10);
        const float Q = fmaf(wy, bot - top, top);

        const bool mask = (Xw > MLO) & (Xw < MHI) & (Yw > MLO) & (Yw < MHI);

        const float tpv = tb[min(y + 1, H_ - 1) * W_ + x];
        const float txm = tb[y * W_ + xm];
        const float txp = tb[y * W_ + xp];
        const float Ft = t0;
        const float gx = txp - txm;
        const float gy = tpv - tm;
        tm = t0; t0 = tpv;

        const float rr = Q - (mask ? Ft : 0.0f);
        const float rX = rr * X, rY = rr * Y;
        const float s = fmaf(X, gx, Y * gy);
        acc0 = fmaf(gx, rX, acc0);
        acc1 = fmaf(gx, rY, acc1);
        acc2 = fmaf(gx, rr, acc2);
        acc3 = fmaf(gy, rX, acc3);
        acc4 = fmaf(gy, rY, acc4);
        acc5 = fmaf(gy, rr, acc5);
        acc6 = fmaf(-s, rX, acc6);
        acc7 = fmaf(-s, rY, acc7);
    }

    __shared__ double red[4][8];
    const int lane = tid & 63, wave = tid >> 6;
    float d[8] = {acc0, acc1, acc2, acc3, acc4, acc5, acc6, acc7};
#pragma unroll
    for (int j = 0; j < 8; ++j) {
        float v = d[j];
        for (int off = 32; off > 0; off >>= 1) v += __shfl_down(v, off, 64);
        if (lane == 0) red[wave][j] = (double)v;
    }
    __syncthreads();
    if (tid < 8) {
        const double v = red[0][tid] + red[1][tid] + red[2][tid] + red[3][tid];
        unsafeAtomicAdd(&g[(size_t)(iter * B_ + b) * 8 + tid], v);
    }
}

__global__ void finish_kernel(const double* __restrict__ invH,
                              const double* __restrict__ g,
                              const float* __restrict__ pstore,
                              const int* __restrict__ gateflag,
                              float* __restrict__ out) {
    const int tid = threadIdx.x;
    if (tid < B_) {
        const int b = tid;
        float pf[8];
        int gate_dummy;
        solve_step(invH + b * 64, g + (size_t)((NITER - 1) * B_ + b) * 8,
                   pstore + (size_t)((NITER - 1) * B_ + b) * 8,
                   gateflag[(NITER - 1) * B_ + b], pf, &gate_dummy);
        for (int j = 0; j < 8; ++j) out[b * 8 + j] = pf[j];
        float* Hout = out + B_ * 8 + b * 9;
        for (int idx = 0; idx < 9; ++idx) {
            float v = (idx < 8) ? pf[idx] : 0.0f;
            if (idx == 0 || idx == 4 || idx == 8) v += 1.0f;
            Hout[idx] = v;
        }
    }
}

extern "C" void kernel_launch(void* const* d_in, const int* in_sizes, int n_in,
                              void* d_out, int out_size, void* d_ws, size_t ws_size,
                              hipStream_t stream) {
    (void)in_sizes; (void)n_in; (void)out_size; (void)ws_size;
    const float* img = (const float*)d_in[0];
    const float* temp = (const float*)d_in[1];
    const float* init_param = (const float*)d_in[2];

    float* out = (float*)d_out;
    char* ws = (char*)d_ws;
    double* g = (double*)(ws + WS_G);
    double* invH = (double*)(ws + WS_INVH);
    double* hmpart = (double*)(ws + WS_HMPART);
    int* cnt = (int*)(ws + WS_CNT);
    float* pstore = (float*)(ws + WS_PSTORE);
    int* gateflag = (int*)(ws + WS_GATE);

    // node 1+2: always run (shared by both paths)
    hipLaunchKernelGGL(prep_zero_kernel, dim3(NBLOCKS), dim3(256), 0, stream,
                       temp, hmpart, g, cnt);
    hipLaunchKernelGGL(solveh_par_kernel, dim3(B_), dim3(256), 0, stream,
                       hmpart, init_param, invH, pstore);

    // node 3: persistent coop kernel (co-residency guarantee; no grid.sync)
    void* kargs[] = {(void*)&img, (void*)&temp, (void*)&init_param,
                     (void*)&out, (void*)&g, (void*)&invH, (void*)&cnt};
    hipError_t err = hipLaunchCooperativeKernel((const void*)persist_kernel,
                                                dim3(NBLOCKS), dim3(256),
                                                kargs, 0, stream);
    if (err != hipSuccess) {
        // fallback: proven R2 chain (iter kernels + finish)
        for (int i = 0; i < NITER; ++i) {
            hipLaunchKernelGGL(iter_kernel, dim3(NBLOCKS), dim3(256), 0, stream,
                               img, temp, init_param, invH, g, pstore, gateflag, i);
        }
        hipLaunchKernelGGL(finish_kernel, dim3(1), dim3(64), 0, stream,
                           invH, g, pstore, gateflag, out);
    }
}

// Round 10
// 356.451 us; speedup vs baseline: 12.1521x; 2.6897x over previous
//
#include <hip/hip_runtime.h>
#include <hip/hip_cooperative_groups.h>
#include <hip/hip_bf16.h>

// OptFlow: forward-additive LK, B=16, k=4, 256x256, 20 iters.
// R8 measured: per-batch 64-wg fenced barrier = ~34us/iter (VALUBusy 20%).
// R9/R10: fence-FREE protocol (all comm via agent-scope atomics; no
//     threadfence, no L2 invalidates), slot-based g partials (no RMW
//     contention, fixed-order deterministic reduce), 256 blocks x 1024 thr
//     (16 blocks/batch, batch pinned to one XCD).
//     (R10 = R9 resubmitted after GPU timeout; correctness re-audited.)

#define B_   16
#define K_   4
#define H_   256
#define W_   256
#define HW_  (H_*W_)
#define NITER 20
#define TOL2 1.0e-6

#define MLO 0.99609375f
#define MHI 254.00390625f

#define PREP_BLOCKS 1024      // prep geometry (unchanged from R8)
#define PERS_BLOCKS 256       // 16 batches x 16 blocks
#define BPB 16                // blocks per batch
#define CNT_STRIDE 32         // ints (128 B): one line per (iter,batch)

// ---------------- ws layout (bytes) ----------------
// region A @0 (327680): hmpart [1024][36] dbl (prep/solveh) THEN
//                       gpart [20][16][16][8] dbl (persist) — disjoint lifetimes
// invH  @ 327680 (8192)
// cnt   @ 335872 (40960)  [20][16][32] int
// gfb   @ 376832 (20480)  fallback g accumulator [20][16][8] dbl
// pstore@ 397312 (10240)  fallback
// gate  @ 407552 (1280)   fallback
#define WS_REGA    0
#define WS_INVH    327680
#define WS_CNT     335872
#define WS_GFB     376832
#define WS_PSTORE  397312
#define WS_GATE    407552

// ===========================================================================
// node 1: zero gfb+cnt, per-block Hm partials (geometry unchanged from R8)
// ===========================================================================
__global__ __launch_bounds__(256, 2) void prep_zero_kernel(const float* __restrict__ temp,
                                                           double* __restrict__ hmpart,
                                                           double* __restrict__ gfb,
                                                           int* __restrict__ cnt) {
    const int bid = blockIdx.x;
    const int tid = threadIdx.x;

    {   // zero gfb (5120 ints) + cnt (10240 ints)
        const int i = bid * 256 + tid;
        if (i < 5120) ((int*)gfb)[i] = 0;
        else if (i < 15360) cnt[i - 5120] = 0;
    }

    const int b = bid & 15;
    const int strip = bid >> 4;
    const int kc = strip >> 4;
    const int ybase = (strip & 15) << 4;
    const float* tb = temp + (size_t)(b * K_ + kc) * HW_;

    const int x = tid;
    const int xm = max(x - 1, 0), xp = min(x + 1, W_ - 1);
    const float X = (float)x - 127.5f;

    float acc[36];
#pragma unroll
    for (int i = 0; i < 36; ++i) acc[i] = 0.0f;

    float tm = tb[max(ybase - 1, 0) * W_ + x];
    float t0 = tb[ybase * W_ + x];

#pragma unroll 4
    for (int r = 0; r < 16; ++r) {
        const int y = ybase + r;
        const float Y = (float)y - 127.5f;
        const float tp = tb[min(y + 1, H_ - 1) * W_ + x];
        const float txm = tb[y * W_ + xm];
        const float txp = tb[y * W_ + xp];
        const float gx = 0.5f * (txp - txm);
        const float gy = 0.5f * (tp - tm);
        tm = t0; t0 = tp;

        const float s = fmaf(X, gx, Y * gy);
        float j[8];
        j[0] = X * gx; j[1] = Y * gx; j[2] = gx;
        j[3] = X * gy; j[4] = Y * gy; j[5] = gy;
        j[6] = -X * s; j[7] = -Y * s;
        int idx = 0;
#pragma unroll
        for (int a = 0; a < 8; ++a)
#pragma unroll
            for (int c = a; c < 8; ++c) {
                acc[idx] = fmaf(j[a], j[c], acc[idx]);
                ++idx;
            }
    }

    __shared__ double red[4][36];
    const int lane = tid & 63, wave = tid >> 6;
#pragma unroll
    for (int i = 0; i < 36; ++i) {
        float v = acc[i];
        for (int off = 32; off > 0; off >>= 1) v += __shfl_down(v, off, 64);
        if (lane == 0) red[wave][i] = (double)v;
    }
    __syncthreads();
    if (tid < 36)
        hmpart[(size_t)bid * 36 + tid] =
            red[0][tid] + red[1][tid] + red[2][tid] + red[3][tid];
}

// ===========================================================================
// node 2: reduce Hm partials + parallel 8x8 GJ inversion, 1 block/batch
// ===========================================================================
__global__ __launch_bounds__(256) void solveh_par_kernel(const double* __restrict__ hmpart,
                                                         const float* __restrict__ init_param,
                                                         double* __restrict__ invH,
                                                         float* __restrict__ pstore) {
    const int b = blockIdx.x;
    const int tid = threadIdx.x;

    __shared__ double s_redq[36][4];
    __shared__ double s_aug[8][16];
    __shared__ int s_pr;
    __shared__ double s_pivinv;

    if (b == 0 && tid < B_ * 8) pstore[tid] = init_param[tid];

    if (tid < 144) {
        const int c = tid >> 2, q = tid & 3;
        double s = 0.0;
        for (int m = 0; m < 16; ++m)
            s += hmpart[(size_t)((q * 16 + m) * 16 + b) * 36 + c];
        s_redq[c][q] = s;
    }
    __syncthreads();
    if (tid < 64) {
        const int j = tid >> 3, k2 = tid & 7;
        s_aug[j][8 + k2] = (j == k2) ? 1.0 : 0.0;
    }
    if (tid < 36) {
        const double sum = s_redq[tid][0] + s_redq[tid][1] + s_redq[tid][2] + s_redq[tid][3];
        int a = 0, base = 0;
        for (; a < 8; ++a) {
            const int next = base + (8 - a);
            if (tid < next) break;
            base = next;
        }
        const int cc = a + (tid - base);
        s_aug[a][cc] = sum;
        s_aug[cc][a] = sum;
    }
    __syncthreads();
    for (int piv = 0; piv < 8; ++piv) {
        if (tid == 0) {
            int pr = piv;
            double pv = fabs(s_aug[piv][piv]);
            for (int rr = piv + 1; rr < 8; ++rr) {
                const double a2 = fabs(s_aug[rr][piv]);
                if (a2 > pv) { pv = a2; pr = rr; }
            }
            s_pr = pr;
        }
        __syncthreads();
        const int pr = s_pr;
        if (pr != piv && tid < 16) {
            const double t1 = s_aug[piv][tid];
            s_aug[piv][tid] = s_aug[pr][tid];
            s_aug[pr][tid] = t1;
        }
        __syncthreads();
        if (tid == 0) s_pivinv = 1.0 / s_aug[piv][piv];
        __syncthreads();
        if (tid < 16) s_aug[piv][tid] *= s_pivinv;
        __syncthreads();
        const int r2 = tid >> 4, cc = tid & 15;
        double f = 0.0;
        if (tid < 128 && r2 != piv) f = s_aug[r2][piv];
        __syncthreads();
        if (tid < 128 && r2 != piv) s_aug[r2][cc] -= f * s_aug[piv][cc];
        __syncthreads();
    }
    if (tid < 64) invH[b * 64 + tid] = s_aug[tid >> 3][8 + (tid & 7)];
}

// ===========================================================================
// node 3: persistent kernel, 256 blocks x 1024 thr. Fence-free per-batch
// barrier; slot-based partials; fixed-order deterministic reduce.
// ===========================================================================
__global__ __launch_bounds__(1024, 4) void persist_kernel(
    const float* __restrict__ img, const float* __restrict__ temp,
    const float* __restrict__ init_param, float* __restrict__ out,
    double* __restrict__ gpart, const double* __restrict__ invH,
    int* __restrict__ cnt)
{
    const int bid = blockIdx.x;
    const int b = bid & 15;           // all 16 blocks of batch b -> XCD b%8
    const int blk = bid >> 4;         // 0..15 within batch
    const int kc = blk >> 2;          // channel
    const int tid = threadIdx.x;
    const int ybase = ((blk & 3) << 6) + ((tid >> 8) << 4);  // 16 contiguous rows

    const float* tb = temp + (size_t)(b * K_ + kc) * HW_;
    const float* ib = img + (size_t)(b * K_ + kc) * HW_;

    const int x = tid & 255;
    const int xmi = max(x - 1, 0), xpi = min(x + 1, W_ - 1);
    const float X = (float)x - 127.5f;
    const int lane = tid & 63, wave = tid >> 6;   // 16 waves

    __shared__ double s_invH[64];
    __shared__ double s_red8[16][8];
    __shared__ double s_gp[16][8];
    __shared__ double s_g[8];

    if (tid < 64) s_invH[tid] = invH[b * 64 + tid];
    __syncthreads();

    float p[8];
#pragma unroll
    for (int j = 0; j < 8; ++j) p[j] = init_param[b * 8 + j];
    int gate = 1;  // ||dp0|| = sqrt(8) > TOL

    for (int it = 0; it < NITER; ++it) {
        // ---- compute this block's partial of g[it][b] ----
        {
            const float a00 = 1.0f + p[0], a01 = p[1];
            const float a10 = p[3], a11 = 1.0f + p[4];
            const float a20 = p[6], a21 = p[7];
            const float a02c = p[2] + 127.5f;
            const float a12c = p[5] + 127.5f;
            const bool affine = (a20 == 0.0f) && (a21 == 0.0f);

            float acc0 = 0.f, acc1 = 0.f, acc2 = 0.f, acc3 = 0.f;
            float acc4 = 0.f, acc5 = 0.f, acc6 = 0.f, acc7 = 0.f;

            float tm = tb[max(ybase - 1, 0) * W_ + x];
            float t0 = tb[ybase * W_ + x];

#pragma unroll 4
            for (int r = 0; r < 16; ++r) {
                const int y = ybase + r;
                const float Y = (float)y - 127.5f;
                float Xw, Yw;
                if (affine) {
                    Xw = fmaf(a00, X, fmaf(a01, Y, a02c));
                    Yw = fmaf(a10, X, fmaf(a11, Y, a12c));
                } else {
                    const float numx = fmaf(a00, X, fmaf(a01, Y, a02c - 127.5f));
                    const float numy = fmaf(a10, X, fmaf(a11, Y, a12c - 127.5f));
                    const float den = fmaf(a20, X, fmaf(a21, Y, 1.0f));
                    Xw = numx / den + 127.5f;
                    Yw = numy / den + 127.5f;
                }

                const float x0f = floorf(Xw), y0f = floorf(Yw);
                const float wx = Xw - x0f, wy = Yw - y0f;
                const int x0 = (int)x0f, y0 = (int)y0f;
                const int x1 = x0 + 1, y1 = y0 + 1;
                const int xc0 = min(max(x0, 0), W_ - 1), xc1 = min(max(x1, 0), W_ - 1);
                const int yc0 = min(max(y0, 0), H_ - 1), yc1 = min(max(y1, 0), H_ - 1);
                const bool vx0 = (unsigned)x0 < (unsigned)W_, vx1 = (unsigned)x1 < (unsigned)W_;
                const bool vy0 = (unsigned)y0 < (unsigned)H_, vy1 = (unsigned)y1 < (unsigned)H_;

                const int idx00 = yc0 * W_ + xc0;
                const int dxi = xc1 - xc0;
                const int dyi = (yc1 - yc0) * W_;
                float v00 = ib[idx00];
                float v01 = ib[idx00 + dxi];
                float v10 = ib[idx00 + dyi];
                float v11 = ib[idx00 + dyi + dxi];
                v00 = (vx0 && vy0) ? v00 : 0.0f;
                v01 = (vx1 && vy0) ? v01 : 0.0f;
                v10 = (vx0 && vy1) ? v10 : 0.0f;
                v11 = (vx1 && vy1) ? v11 : 0.0f;

                const float top = fmaf(wx, v01 - v00, v00);
                const float bot = fmaf(wx, v11 - v10, v10);
                const float Q = fmaf(wy, bot - top, top);

                const bool mask = (Xw > MLO) & (Xw < MHI) & (Yw > MLO) & (Yw < MHI);

                const float tpv = tb[min(y + 1, H_ - 1) * W_ + x];
                const float txm = tb[y * W_ + xmi];
                const float txp = tb[y * W_ + xpi];
                const float Ft = t0;
                const float gx = txp - txm;   // 2x grads (exact), 0.5 in solve
                const float gy = tpv - tm;
                tm = t0; t0 = tpv;

                const float rr = Q - (mask ? Ft : 0.0f);
                const float rX = rr * X, rY = rr * Y;
                const float s = fmaf(X, gx, Y * gy);
                acc0 = fmaf(gx, rX, acc0);
                acc1 = fmaf(gx, rY, acc1);
                acc2 = fmaf(gx, rr, acc2);
                acc3 = fmaf(gy, rX, acc3);
                acc4 = fmaf(gy, rY, acc4);
                acc5 = fmaf(gy, rr, acc5);
                acc6 = fmaf(-s, rX, acc6);
                acc7 = fmaf(-s, rY, acc7);
            }

            float d8[8] = {acc0, acc1, acc2, acc3, acc4, acc5, acc6, acc7};
#pragma unroll
            for (int j = 0; j < 8; ++j) {
                float v = d8[j];
                for (int off = 32; off > 0; off >>= 1) v += __shfl_down(v, off, 64);
                if (lane == 0) s_red8[wave][j] = (double)v;
            }
            __syncthreads();
            if (tid < 8) {  // fixed-order 16-wave sum -> agent-scope slot store
                double v = 0.0;
#pragma unroll
                for (int w = 0; w < 16; ++w) v += s_red8[w][tid];
                __hip_atomic_store(&gpart[(size_t)(((it * B_ + b) * BPB) + blk) * 8 + tid],
                                   v, __ATOMIC_RELAXED, __HIP_MEMORY_SCOPE_AGENT);
            }
        }

        // ---- fence-free barrier: syncthreads drains stores (vmcnt 0) ----
        __syncthreads();
        int* c = cnt + (it * B_ + b) * CNT_STRIDE;
        if (tid == 0) {
            __hip_atomic_fetch_add(c, 1, __ATOMIC_RELAXED, __HIP_MEMORY_SCOPE_AGENT);
            while (__hip_atomic_load(c, __ATOMIC_RELAXED, __HIP_MEMORY_SCOPE_AGENT) < BPB)
                __builtin_amdgcn_s_sleep(2);
        }
        __syncthreads();

        // ---- gather all 16 slots (agent loads bypass caches), reduce fixed-order
        if (tid < 128) {
            const int m = tid >> 3, j = tid & 7;
            s_gp[m][j] = __hip_atomic_load(
                &gpart[(size_t)(((it * B_ + b) * BPB) + m) * 8 + j],
                __ATOMIC_RELAXED, __HIP_MEMORY_SCOPE_AGENT);
        }
        __syncthreads();
        if (tid < 8) {
            double v = 0.0;
#pragma unroll
            for (int m = 0; m < 16; ++m) v += s_gp[m][tid];
            s_g[tid] = v;
        }
        __syncthreads();

        // ---- solve (bit-identical across the batch's blocks) ----
        {
            double nsq = 0.0;
#pragma unroll
            for (int j = 0; j < 6; ++j) {
                double s = 0.0;
#pragma unroll
                for (int k2 = 0; k2 < 8; ++k2) s += s_invH[j * 8 + k2] * s_g[k2];
                const double dpj = 0.5 * s;  // exact compensation for 2x grads
                nsq += dpj * dpj;
                p[j] -= (float)dpj;
            }
            gate = (nsq > TOL2) ? 1 : 0;
        }
        if (!gate) break;  // whole batch breaks together
    }

    if (blk == 0) {
        if (tid < 8) out[b * 8 + tid] = p[tid];
        if (tid < 9) {
            float v = (tid < 8) ? p[tid] : 0.0f;
            if (tid == 0 || tid == 4 || tid == 8) v += 1.0f;
            out[B_ * 8 + b * 9 + tid] = v;
        }
    }
}

// ===========================================================================
// fallback chain (R2/R8 proven) — only if cooperative launch is rejected.
// ===========================================================================
__device__ __forceinline__ void solve_step(const double* __restrict__ invHb,
                                           const double* __restrict__ gprev,
                                           const float* __restrict__ pprev,
                                           int gate_prev, float* p, int* gate_out) {
    double dp[8];
#pragma unroll
    for (int j = 0; j < 8; ++j) dp[j] = 0.0;
    if (gate_prev) {
#pragma unroll
        for (int j = 0; j < 6; ++j) {
            double s = 0.0;
#pragma unroll
            for (int k = 0; k < 8; ++k) s += invHb[j * 8 + k] * gprev[k];
            dp[j] = 0.5 * s;
        }
    }
    double nsq = 0.0;
#pragma unroll
    for (int j = 0; j < 8; ++j) nsq += dp[j] * dp[j];
    *gate_out = (nsq > TOL2) ? 1 : 0;
#pragma unroll
    for (int j = 0; j < 8; ++j) p[j] = pprev[j] - (float)dp[j];
}

__global__ __launch_bounds__(256, 4) void iter_kernel(const float* __restrict__ img,
                                                      const float* __restrict__ temp,
                                                      const float* __restrict__ init_param,
                                                      const double* __restrict__ invH,
                                                      double* __restrict__ g,
                                                      float* __restrict__ pstore,
                                                      int* __restrict__ gateflag,
                                                      int iter) {
    const int bid = blockIdx.x;
    const int b = bid & 15;
    const int strip = bid >> 4;
    const int tid = threadIdx.x;

    float p[8];
    int gate;
    if (iter == 0) {
#pragma unroll
        for (int j = 0; j < 8; ++j) p[j] = init_param[b * 8 + j];
        gate = 1;
    } else {
        solve_step(invH + b * 64, g + (size_t)((iter - 1) * B_ + b) * 8,
                   pstore + (size_t)((iter - 1) * B_ + b) * 8,
                   gateflag[(iter - 1) * B_ + b], p, &gate);
    }
    if (tid < 8) pstore[(size_t)(iter * B_ + b) * 8 + tid] = p[tid];
    if (tid == 0) gateflag[iter * B_ + b] = gate;
    if (!gate) return;

    const int kc = strip >> 4;
    const int ybase = (strip & 15) << 4;
    const float* ib = img + (size_t)(b * K_ + kc) * HW_;
    const float* tb = temp + (size_t)(b * K_ + kc) * HW_;

    const float a00 = 1.0f + p[0], a01 = p[1];
    const float a10 = p[3], a11 = 1.0f + p[4];
    const float a20 = p[6], a21 = p[7];
    const float a02c = p[2] + 127.5f;
    const float a12c = p[5] + 127.5f;
    const bool affine = (a20 == 0.0f) && (a21 == 0.0f);

    const int x = tid;
    const int xm = max(x - 1, 0), xp = min(x + 1, W_ - 1);
    const float X = (float)x - 127.5f;

    float acc0 = 0.f, acc1 = 0.f, acc2 = 0.f, acc3 = 0.f;
    float acc4 = 0.f, acc5 = 0.f, acc6 = 0.f, acc7 = 0.f;

    float tm = tb[max(ybase - 1, 0) * W_ + x];
    float t0 = tb[ybase * W_ + x];

#pragma unroll 4
    for (int r = 0; r < 16; ++r) {
        const int y = ybase + r;
        const float Y = (float)y - 127.5f;
        float Xw, Yw;
        if (affine) {
            Xw = fmaf(a00, X, fmaf(a01, Y, a02c));
            Yw = fmaf(a10, X, fmaf(a11, Y, a12c));
        } else {
            const float numx = fmaf(a00, X, fmaf(a01, Y, a02c - 127.5f));
            const float numy = fmaf(a10, X, fmaf(a11, Y, a12c - 127.5f));
            const float den = fmaf(a20, X, fmaf(a21, Y, 1.0f));
            Xw = numx / den + 127.5f;
            Yw = numy / den + 127.5f;
        }

        const float x0f = floorf(Xw), y0f = floorf(Yw);
        const float wx = Xw - x0f, wy = Yw - y0f;
        const int x0 = (int)x0f, y0 = (int)y0f;
        const int x1 = x0 + 1, y1 = y0 + 1;
        const int xc0 = min(max(x0, 0), W_ - 1), xc1 = min(max(x1, 0), W_ - 1);
        const int yc0 = min(max(y0, 0), H_ - 1), yc1 = min(max(y1, 0), H_ - 1);
        const bool vx0 = (unsigned)x0 < (unsigned)W_, vx1 = (unsigned)x1 < (unsigned)W_;
        const bool vy0 = (unsigned)y0 < (unsigned)H_, vy1 = (unsigned)y1 < (unsigned)H_;

        const int idx00 = yc0 * W_ + xc0;
        const int dxi = xc1 - xc0;
        const int dyi = (yc1 - yc0) * W_;
        float v00 = ib[idx00];
        float v01 = ib[idx00 + dxi];
        float v10 = ib[idx00 + dyi];
        float v11 = ib[idx00 + dyi + dxi];
        v00 = (vx0 && vy0) ? v00 : 0.0f;
        v01 = (vx1 && vy0) ? v01 : 0.0f;
        v10 = (vx0 && vy1) ? v10 : 0.0f;
        v11 = (vx1 && vy1) ? v11 : 0.0f;

        const float top = fmaf(wx, v01 - v00, v00);
        const float bot = fmaf(wx, v11 - v10, v10);
        const float Q = fmaf(wy, bot - top, top);

        const bool mask = (Xw > MLO) & (Xw < MHI) & (Yw > MLO) & (Yw < MHI);

        const float tpv = tb[min(y + 1, H_ - 1) * W_ + x];
        const float txm = tb[y * W_ + xm];
        const float txp = tb[y * W_ + xp];
        const float Ft = t0;
        const float gx = txp - txm;
        const float gy = tpv - tm;
        tm = t0; t0 = tpv;

        const float rr = Q - (mask ? Ft : 0.0f);
        const float rX = rr * X, rY = rr * Y;
        const float s = fmaf(X, gx, Y * gy);
        acc0 = fmaf(gx, rX, acc0);
        acc1 = fmaf(gx, rY, acc1);
        acc2 = fmaf(gx, rr, acc2);
        acc3 = fmaf(gy, rX, acc3);
        acc4 = fmaf(gy, rY, acc4);
        acc5 = fmaf(gy, rr, acc5);
        acc6 = fmaf(-s, rX, acc6);
        acc7 = fmaf(-s, rY, acc7);
    }

    __shared__ double red[4][8];
    const int lane = tid & 63, wave = tid >> 6;
    float d[8] = {acc0, acc1, acc2, acc3, acc4, acc5, acc6, acc7};
#pragma unroll
    for (int j = 0; j < 8; ++j) {
        float v = d[j];
        for (int off = 32; off > 0; off >>= 1) v += __shfl_down(v, off, 64);
        if (lane == 0) red[wave][j] = (double)v;
    }
    __syncthreads();
    if (tid < 8) {
        const double v = red[0][tid] + red[1][tid] + red[2][tid] + red[3][tid];
        unsafeAtomicAdd(&g[(size_t)(iter * B_ + b) * 8 + tid], v);
    }
}

__global__ void finish_kernel(const double* __restrict__ invH,
                              const double* __restrict__ g,
                              const float* __restrict__ pstore,
                              const int* __restrict__ gateflag,
                              float* __restrict__ out) {
    const int tid = threadIdx.x;
    if (tid < B_) {
        const int b = tid;
        float pf[8];
        int gate_dummy;
        solve_step(invH + b * 64, g + (size_t)((NITER - 1) * B_ + b) * 8,
                   pstore + (size_t)((NITER - 1) * B_ + b) * 8,
                   gateflag[(NITER - 1) * B_ + b], pf, &gate_dummy);
        for (int j = 0; j < 8; ++j) out[b * 8 + j] = pf[j];
        float* Hout = out + B_ * 8 + b * 9;
        for (int idx = 0; idx < 9; ++idx) {
            float v = (idx < 8) ? pf[idx] : 0.0f;
            if (idx == 0 || idx == 4 || idx == 8) v += 1.0f;
            Hout[idx] = v;
        }
    }
}

extern "C" void kernel_launch(void* const* d_in, const int* in_sizes, int n_in,
                              void* d_out, int out_size, void* d_ws, size_t ws_size,
                              hipStream_t stream) {
    (void)in_sizes; (void)n_in; (void)out_size; (void)ws_size;
    const float* img = (const float*)d_in[0];
    const float* temp = (const float*)d_in[1];
    const float* init_param = (const float*)d_in[2];

    float* out = (float*)d_out;
    char* ws = (char*)d_ws;
    double* rega = (double*)(ws + WS_REGA);     // hmpart then gpart
    double* invH = (double*)(ws + WS_INVH);
    int* cnt = (int*)(ws + WS_CNT);
    double* gfb = (double*)(ws + WS_GFB);
    float* pstore = (float*)(ws + WS_PSTORE);
    int* gateflag = (int*)(ws + WS_GATE);

    hipLaunchKernelGGL(prep_zero_kernel, dim3(PREP_BLOCKS), dim3(256), 0, stream,
                       temp, rega, gfb, cnt);
    hipLaunchKernelGGL(solveh_par_kernel, dim3(B_), dim3(256), 0, stream,
                       rega, init_param, invH, pstore);

    void* kargs[] = {(void*)&img, (void*)&temp, (void*)&init_param,
                     (void*)&out, (void*)&rega, (void*)&invH, (void*)&cnt};
    hipError_t err = hipLaunchCooperativeKernel((const void*)persist_kernel,
                                                dim3(PERS_BLOCKS), dim3(1024),
                                                kargs, 0, stream);
    if (err != hipSuccess) {
        // fallback: proven multi-kernel chain
        for (int i = 0; i < NITER; ++i) {
            hipLaunchKernelGGL(iter_kernel, dim3(1024), dim3(256), 0, stream,
                               img, temp, init_param, invH, gfb, pstore, gateflag, i);
        }
        hipLaunchKernelGGL(finish_kernel, dim3(1), dim3(64), 0, stream,
                           invH, gfb, pstore, gateflag, out);
    }
}